// Round 1
// baseline (4727.242 us; speedup 1.0000x reference)
//
#include <hip/hip_runtime.h>

#define NN 100000
#define NE 800000
#define NG 128
#define U  128
#define NGIN 3

// ---------------------------------------------------------------------------
// scatter: agg[dst] += h[src] * w   (one thread per (edge, 4-unit group))
// ---------------------------------------------------------------------------
__global__ __launch_bounds__(256) void scatter_k(const float* __restrict__ h,
                                                 const int* __restrict__ ei,
                                                 const float* __restrict__ ew,
                                                 float* __restrict__ agg) {
    int idx = blockIdx.x * 256 + threadIdx.x;
    int e = idx >> 5;
    if (e >= NE) return;
    int u4 = (idx & 31) << 2;
    int d = ei[e];         // edge_index[0][e] = dst
    int s = ei[NE + e];    // edge_index[1][e] = src
    float w = ew[e];
    float4 hv = *reinterpret_cast<const float4*>(h + (size_t)s * U + u4);
    float* ap = agg + (size_t)d * U + u4;
    unsafeAtomicAdd(ap + 0, hv.x * w);
    unsafeAtomicAdd(ap + 1, hv.y * w);
    unsafeAtomicAdd(ap + 2, hv.z * w);
    unsafeAtomicAdd(ap + 3, hv.w * w);
}

// ---------------------------------------------------------------------------
// dense: C[row, :] = act(A @ W + b)
// MODE 0: A = 1.5*h + agg, epilogue relu                 -> z1
// MODE 1: A = z1,          epilogue bn+relu + pool-atomic -> h
// 32-row tile per block, 256 threads, k chunked by 32.
// thread (rg = tid>>5, cg = tid&31) computes rows rg*4..rg*4+3, cols cg*4..+3
// ---------------------------------------------------------------------------
template <int MODE>
__global__ __launch_bounds__(256) void dense_k(const float* __restrict__ A0,
                                               const float* __restrict__ A1,
                                               const float* __restrict__ W,
                                               const float* __restrict__ bias,
                                               const float* __restrict__ gamma,
                                               const float* __restrict__ beta,
                                               const float* __restrict__ mean,
                                               const float* __restrict__ var,
                                               const int* __restrict__ gidx,
                                               float* __restrict__ outp,
                                               float* __restrict__ pooled,
                                               int pool_off) {
    __shared__ float sW[32][128];  // [k][c] chunk, 16 KB
    __shared__ float sA[32][32];   // [row][k] chunk, 4 KB
    const int tid = threadIdx.x;
    const int row0 = blockIdx.x * 32;
    const int rg = tid >> 5;
    const int c0 = (tid & 31) << 2;

    float4 acc[4];
#pragma unroll
    for (int i = 0; i < 4; ++i) acc[i] = make_float4(0.f, 0.f, 0.f, 0.f);

    for (int kc = 0; kc < 4; ++kc) {
        const int k0 = kc * 32;
#pragma unroll
        for (int j = 0; j < 16; ++j) {
            int idx = tid + j * 256;
            int k = idx >> 7, c = idx & 127;
            sW[k][c] = W[(size_t)(k0 + k) * U + c];
        }
#pragma unroll
        for (int j = 0; j < 4; ++j) {
            int idx = tid + j * 256;
            int r = idx >> 5, kk = idx & 31;
            size_t off = (size_t)(row0 + r) * U + k0 + kk;
            float v;
            if (MODE == 0) v = 1.5f * A0[off] + A1[off];
            else           v = A0[off];
            sA[r][kk] = v;
        }
        __syncthreads();
#pragma unroll
        for (int kk = 0; kk < 32; kk += 4) {
            float4 w0 = *reinterpret_cast<const float4*>(&sW[kk + 0][c0]);
            float4 w1 = *reinterpret_cast<const float4*>(&sW[kk + 1][c0]);
            float4 w2 = *reinterpret_cast<const float4*>(&sW[kk + 2][c0]);
            float4 w3 = *reinterpret_cast<const float4*>(&sW[kk + 3][c0]);
#pragma unroll
            for (int i = 0; i < 4; ++i) {
                float4 a = *reinterpret_cast<const float4*>(&sA[rg * 4 + i][kk]);
                acc[i].x = fmaf(a.w, w3.x, fmaf(a.z, w2.x, fmaf(a.y, w1.x, fmaf(a.x, w0.x, acc[i].x))));
                acc[i].y = fmaf(a.w, w3.y, fmaf(a.z, w2.y, fmaf(a.y, w1.y, fmaf(a.x, w0.y, acc[i].y))));
                acc[i].z = fmaf(a.w, w3.z, fmaf(a.z, w2.z, fmaf(a.y, w1.z, fmaf(a.x, w0.z, acc[i].z))));
                acc[i].w = fmaf(a.w, w3.w, fmaf(a.z, w2.w, fmaf(a.y, w1.w, fmaf(a.x, w0.w, acc[i].w))));
            }
        }
        __syncthreads();
    }

    float4 b = *reinterpret_cast<const float4*>(&bias[c0]);
    if (MODE == 0) {
#pragma unroll
        for (int i = 0; i < 4; ++i) {
            float4 v;
            v.x = fmaxf(acc[i].x + b.x, 0.f);
            v.y = fmaxf(acc[i].y + b.y, 0.f);
            v.z = fmaxf(acc[i].z + b.z, 0.f);
            v.w = fmaxf(acc[i].w + b.w, 0.f);
            *reinterpret_cast<float4*>(outp + (size_t)(row0 + rg * 4 + i) * U + c0) = v;
        }
    } else {
        float4 m  = *reinterpret_cast<const float4*>(&mean[c0]);
        float4 vv = *reinterpret_cast<const float4*>(&var[c0]);
        float4 g4 = *reinterpret_cast<const float4*>(&gamma[c0]);
        float4 bt = *reinterpret_cast<const float4*>(&beta[c0]);
        float4 scl;
        scl.x = g4.x * rsqrtf(vv.x + 1e-3f);
        scl.y = g4.y * rsqrtf(vv.y + 1e-3f);
        scl.z = g4.z * rsqrtf(vv.z + 1e-3f);
        scl.w = g4.w * rsqrtf(vv.w + 1e-3f);
        float4 hv[4];
#pragma unroll
        for (int i = 0; i < 4; ++i) {
            float4 v;
            v.x = fmaxf((acc[i].x + b.x - m.x) * scl.x + bt.x, 0.f);
            v.y = fmaxf((acc[i].y + b.y - m.y) * scl.y + bt.y, 0.f);
            v.z = fmaxf((acc[i].z + b.z - m.z) * scl.z + bt.z, 0.f);
            v.w = fmaxf((acc[i].w + b.w - m.w) * scl.w + bt.w, 0.f);
            hv[i] = v;
            *reinterpret_cast<float4*>(outp + (size_t)(row0 + rg * 4 + i) * U + c0) = v;
        }
        // pooled[g, pool_off + c] += h (node_graph_index is sorted)
        int r0 = row0 + rg * 4;
        int ga = gidx[r0], gb = gidx[r0 + 3];
        if (ga == gb) {
            float* pp = pooled + (size_t)ga * (NGIN * U) + pool_off + c0;
            unsafeAtomicAdd(pp + 0, hv[0].x + hv[1].x + hv[2].x + hv[3].x);
            unsafeAtomicAdd(pp + 1, hv[0].y + hv[1].y + hv[2].y + hv[3].y);
            unsafeAtomicAdd(pp + 2, hv[0].z + hv[1].z + hv[2].z + hv[3].z);
            unsafeAtomicAdd(pp + 3, hv[0].w + hv[1].w + hv[2].w + hv[3].w);
        } else {
#pragma unroll
            for (int i = 0; i < 4; ++i) {
                float* pp = pooled + (size_t)gidx[r0 + i] * (NGIN * U) + pool_off + c0;
                unsafeAtomicAdd(pp + 0, hv[i].x);
                unsafeAtomicAdd(pp + 1, hv[i].y);
                unsafeAtomicAdd(pp + 2, hv[i].z);
                unsafeAtomicAdd(pp + 3, hv[i].w);
            }
        }
    }
}

// ---------------------------------------------------------------------------
// g = relu(pooled @ Wm1 + bm1): one block per graph, 128 threads
// ---------------------------------------------------------------------------
__global__ __launch_bounds__(128) void mlp1_k(const float* __restrict__ pooled,
                                              const float* __restrict__ Wm1,
                                              const float* __restrict__ bm1,
                                              float* __restrict__ g) {
    __shared__ float sp[NGIN * U];
    int gi = blockIdx.x, c = threadIdx.x;
    for (int j = c; j < NGIN * U; j += 128) sp[j] = pooled[(size_t)gi * (NGIN * U) + j];
    __syncthreads();
    float acc = bm1[c];
    for (int k = 0; k < NGIN * U; ++k) acc = fmaf(sp[k], Wm1[(size_t)k * 128 + c], acc);
    g[gi * 128 + c] = fmaxf(acc, 0.f);
}

// ---------------------------------------------------------------------------
// logits = g @ Wm2 + bm2: 2048 outputs
// ---------------------------------------------------------------------------
__global__ __launch_bounds__(256) void mlp2_k(const float* __restrict__ g,
                                              const float* __restrict__ Wm2,
                                              const float* __restrict__ bm2,
                                              float* __restrict__ out) {
    int idx = blockIdx.x * 256 + threadIdx.x;
    int gi = idx >> 4, c = idx & 15;
    float acc = bm2[c];
    for (int k = 0; k < 128; ++k) acc = fmaf(g[gi * 128 + k], Wm2[k * 16 + c], acc);
    out[gi * 16 + c] = acc;
}

extern "C" void kernel_launch(void* const* d_in, const int* in_sizes, int n_in,
                              void* d_out, int out_size, void* d_ws, size_t ws_size,
                              hipStream_t stream) {
    const float* x   = (const float*)d_in[0];
    const int*   ei  = (const int*)d_in[1];
    const float* ew  = (const float*)d_in[2];
    const int*   gix = (const int*)d_in[3];
    const float* W1  = (const float*)d_in[4];
    const float* b1  = (const float*)d_in[5];
    const float* W2  = (const float*)d_in[6];
    const float* b2  = (const float*)d_in[7];
    const float* gam = (const float*)d_in[8];
    const float* bet = (const float*)d_in[9];
    const float* bmn = (const float*)d_in[10];
    const float* bvr = (const float*)d_in[11];
    const float* Wm1 = (const float*)d_in[12];
    const float* bm1 = (const float*)d_in[13];
    const float* Wm2 = (const float*)d_in[14];
    const float* bm2 = (const float*)d_in[15];
    float* out = (float*)d_out;

    // workspace layout (fp32): h [NN*U] | aggz [NN*U] | pooled [NG*384] | g [NG*128]
    float* h      = (float*)d_ws;
    float* aggz   = h + (size_t)NN * U;
    float* pooled = aggz + (size_t)NN * U;
    float* gbuf   = pooled + (size_t)NG * (NGIN * U);

    hipMemsetAsync(pooled, 0, (size_t)NG * (NGIN * U) * sizeof(float), stream);
    for (int i = 0; i < NGIN; ++i) {
        const float* hin = (i == 0) ? x : h;
        hipMemsetAsync(aggz, 0, (size_t)NN * U * sizeof(float), stream);
        scatter_k<<<(NE * 32) / 256, 256, 0, stream>>>(hin, ei, ew, aggz);
        // z1 = relu((1.5h + agg) @ W1 + b1)  -> written in-place over aggz
        dense_k<0><<<NN / 32, 256, 0, stream>>>(hin, aggz, W1 + (size_t)i * U * U, b1 + i * U,
                                                nullptr, nullptr, nullptr, nullptr, nullptr,
                                                aggz, nullptr, 0);
        // h = relu(bn(z1 @ W2 + b2)); pooled += h
        dense_k<1><<<NN / 32, 256, 0, stream>>>(aggz, nullptr, W2 + (size_t)i * U * U, b2 + i * U,
                                                gam + i * U, bet + i * U, bmn + i * U, bvr + i * U,
                                                gix, h, pooled, i * U);
    }
    mlp1_k<<<NG, 128, 0, stream>>>(pooled, Wm1, bm1, gbuf);
    mlp2_k<<<(NG * 16) / 256, 256, 0, stream>>>(gbuf, Wm2, bm2, out);
}

// Round 2
// 1214.710 us; speedup vs baseline: 3.8917x; 3.8917x over previous
//
#include <hip/hip_runtime.h>

#define NN 100000
#define NE 800000
#define NG 128
#define U  128
#define NGIN 3

// ---------------------------------------------------------------------------
// edge sort by dst: histogram -> exclusive scan -> bin
// ---------------------------------------------------------------------------
__global__ __launch_bounds__(256) void hist_k(const int* __restrict__ ei,
                                              int* __restrict__ hist) {
    int e = blockIdx.x * 256 + threadIdx.x;
    if (e < NE) atomicAdd(&hist[ei[e]], 1);
}

__global__ __launch_bounds__(1024) void scan_k(const int* __restrict__ hist,
                                               int* __restrict__ rowptr) {
    __shared__ int tmp[1024];
    __shared__ int carry;
    if (threadIdx.x == 0) carry = 0;
    __syncthreads();
    for (int base = 0; base < NN; base += 1024) {
        int i = base + threadIdx.x;
        int v = (i < NN) ? hist[i] : 0;
        tmp[threadIdx.x] = v;
        __syncthreads();
        for (int off = 1; off < 1024; off <<= 1) {
            int t = (threadIdx.x >= off) ? tmp[threadIdx.x - off] : 0;
            __syncthreads();
            tmp[threadIdx.x] += t;
            __syncthreads();
        }
        int incl = tmp[threadIdx.x];
        if (i < NN) rowptr[i] = carry + incl - v;   // exclusive
        int total = tmp[1023];
        __syncthreads();
        if (threadIdx.x == 0) carry += total;
        __syncthreads();
    }
    if (threadIdx.x == 0) rowptr[NN] = NE;
}

__global__ __launch_bounds__(256) void bin_k(const int* __restrict__ ei,
                                             const float* __restrict__ ew,
                                             int* __restrict__ cursor,
                                             int* __restrict__ src_s,
                                             float* __restrict__ w_s) {
    int e = blockIdx.x * 256 + threadIdx.x;
    if (e >= NE) return;
    int d = ei[e];
    int pos = atomicAdd(&cursor[d], 1);
    src_s[pos] = ei[NE + e];
    w_s[pos] = ew[e];
}

// ---------------------------------------------------------------------------
// gather: z[n] = 1.5*h[n] + sum_{e in row n} h[src[e]] * w[e]
// one wave per node, lane owns 2 units (float2, coalesced 512B row reads)
// ---------------------------------------------------------------------------
__global__ __launch_bounds__(256) void gather_k(const float* __restrict__ h,
                                                const int* __restrict__ src_s,
                                                const float* __restrict__ w_s,
                                                const int* __restrict__ rowptr,
                                                float* __restrict__ z) {
    int node = blockIdx.x * 4 + (threadIdx.x >> 6);
    if (node >= NN) return;
    int lane = threadIdx.x & 63;
    int beg = rowptr[node], end = rowptr[node + 1];
    float2 acc = make_float2(0.f, 0.f);
    for (int e = beg; e < end; ++e) {
        int s = src_s[e];
        float w = w_s[e];
        float2 hv = *reinterpret_cast<const float2*>(h + (size_t)s * U + lane * 2);
        acc.x = fmaf(hv.x, w, acc.x);
        acc.y = fmaf(hv.y, w, acc.y);
    }
    float2 hn = *reinterpret_cast<const float2*>(h + (size_t)node * U + lane * 2);
    acc.x = fmaf(1.5f, hn.x, acc.x);
    acc.y = fmaf(1.5f, hn.y, acc.y);
    *reinterpret_cast<float2*>(z + (size_t)node * U + lane * 2) = acc;
}

// ---------------------------------------------------------------------------
// dense: C[row, :] = act(A @ W + b)
// MODE 0: epilogue relu                   -> z1
// MODE 1: epilogue bn+relu + pool-atomic  -> h
// ---------------------------------------------------------------------------
template <int MODE>
__global__ __launch_bounds__(256) void dense_k(const float* __restrict__ A0,
                                               const float* __restrict__ W,
                                               const float* __restrict__ bias,
                                               const float* __restrict__ gamma,
                                               const float* __restrict__ beta,
                                               const float* __restrict__ mean,
                                               const float* __restrict__ var,
                                               const int* __restrict__ gidx,
                                               float* __restrict__ outp,
                                               float* __restrict__ pooled,
                                               int pool_off) {
    __shared__ float sW[32][128];
    __shared__ float sA[32][32];
    const int tid = threadIdx.x;
    const int row0 = blockIdx.x * 32;
    const int rg = tid >> 5;
    const int c0 = (tid & 31) << 2;

    float4 acc[4];
#pragma unroll
    for (int i = 0; i < 4; ++i) acc[i] = make_float4(0.f, 0.f, 0.f, 0.f);

    for (int kc = 0; kc < 4; ++kc) {
        const int k0 = kc * 32;
#pragma unroll
        for (int j = 0; j < 16; ++j) {
            int idx = tid + j * 256;
            int k = idx >> 7, c = idx & 127;
            sW[k][c] = W[(size_t)(k0 + k) * U + c];
        }
#pragma unroll
        for (int j = 0; j < 4; ++j) {
            int idx = tid + j * 256;
            int r = idx >> 5, kk = idx & 31;
            sA[r][kk] = A0[(size_t)(row0 + r) * U + k0 + kk];
        }
        __syncthreads();
#pragma unroll
        for (int kk = 0; kk < 32; kk += 4) {
            float4 w0 = *reinterpret_cast<const float4*>(&sW[kk + 0][c0]);
            float4 w1 = *reinterpret_cast<const float4*>(&sW[kk + 1][c0]);
            float4 w2 = *reinterpret_cast<const float4*>(&sW[kk + 2][c0]);
            float4 w3 = *reinterpret_cast<const float4*>(&sW[kk + 3][c0]);
#pragma unroll
            for (int i = 0; i < 4; ++i) {
                float4 a = *reinterpret_cast<const float4*>(&sA[rg * 4 + i][kk]);
                acc[i].x = fmaf(a.w, w3.x, fmaf(a.z, w2.x, fmaf(a.y, w1.x, fmaf(a.x, w0.x, acc[i].x))));
                acc[i].y = fmaf(a.w, w3.y, fmaf(a.z, w2.y, fmaf(a.y, w1.y, fmaf(a.x, w0.y, acc[i].y))));
                acc[i].z = fmaf(a.w, w3.z, fmaf(a.z, w2.z, fmaf(a.y, w1.z, fmaf(a.x, w0.z, acc[i].z))));
                acc[i].w = fmaf(a.w, w3.w, fmaf(a.z, w2.w, fmaf(a.y, w1.w, fmaf(a.x, w0.w, acc[i].w))));
            }
        }
        __syncthreads();
    }

    float4 b = *reinterpret_cast<const float4*>(&bias[c0]);
    if (MODE == 0) {
#pragma unroll
        for (int i = 0; i < 4; ++i) {
            float4 v;
            v.x = fmaxf(acc[i].x + b.x, 0.f);
            v.y = fmaxf(acc[i].y + b.y, 0.f);
            v.z = fmaxf(acc[i].z + b.z, 0.f);
            v.w = fmaxf(acc[i].w + b.w, 0.f);
            *reinterpret_cast<float4*>(outp + (size_t)(row0 + rg * 4 + i) * U + c0) = v;
        }
    } else {
        float4 m  = *reinterpret_cast<const float4*>(&mean[c0]);
        float4 vv = *reinterpret_cast<const float4*>(&var[c0]);
        float4 g4 = *reinterpret_cast<const float4*>(&gamma[c0]);
        float4 bt = *reinterpret_cast<const float4*>(&beta[c0]);
        float4 scl;
        scl.x = g4.x * rsqrtf(vv.x + 1e-3f);
        scl.y = g4.y * rsqrtf(vv.y + 1e-3f);
        scl.z = g4.z * rsqrtf(vv.z + 1e-3f);
        scl.w = g4.w * rsqrtf(vv.w + 1e-3f);
        float4 hv[4];
#pragma unroll
        for (int i = 0; i < 4; ++i) {
            float4 v;
            v.x = fmaxf((acc[i].x + b.x - m.x) * scl.x + bt.x, 0.f);
            v.y = fmaxf((acc[i].y + b.y - m.y) * scl.y + bt.y, 0.f);
            v.z = fmaxf((acc[i].z + b.z - m.z) * scl.z + bt.z, 0.f);
            v.w = fmaxf((acc[i].w + b.w - m.w) * scl.w + bt.w, 0.f);
            hv[i] = v;
            *reinterpret_cast<float4*>(outp + (size_t)(row0 + rg * 4 + i) * U + c0) = v;
        }
        int r0 = row0 + rg * 4;
        int ga = gidx[r0], gb = gidx[r0 + 3];
        if (ga == gb) {
            float* pp = pooled + (size_t)ga * (NGIN * U) + pool_off + c0;
            unsafeAtomicAdd(pp + 0, hv[0].x + hv[1].x + hv[2].x + hv[3].x);
            unsafeAtomicAdd(pp + 1, hv[0].y + hv[1].y + hv[2].y + hv[3].y);
            unsafeAtomicAdd(pp + 2, hv[0].z + hv[1].z + hv[2].z + hv[3].z);
            unsafeAtomicAdd(pp + 3, hv[0].w + hv[1].w + hv[2].w + hv[3].w);
        } else {
#pragma unroll
            for (int i = 0; i < 4; ++i) {
                float* pp = pooled + (size_t)gidx[r0 + i] * (NGIN * U) + pool_off + c0;
                unsafeAtomicAdd(pp + 0, hv[i].x);
                unsafeAtomicAdd(pp + 1, hv[i].y);
                unsafeAtomicAdd(pp + 2, hv[i].z);
                unsafeAtomicAdd(pp + 3, hv[i].w);
            }
        }
    }
}

// ---------------------------------------------------------------------------
// g = relu(pooled @ Wm1 + bm1): one block per graph, 128 threads
// ---------------------------------------------------------------------------
__global__ __launch_bounds__(128) void mlp1_k(const float* __restrict__ pooled,
                                              const float* __restrict__ Wm1,
                                              const float* __restrict__ bm1,
                                              float* __restrict__ g) {
    __shared__ float sp[NGIN * U];
    int gi = blockIdx.x, c = threadIdx.x;
    for (int j = c; j < NGIN * U; j += 128) sp[j] = pooled[(size_t)gi * (NGIN * U) + j];
    __syncthreads();
    float acc = bm1[c];
    for (int k = 0; k < NGIN * U; ++k) acc = fmaf(sp[k], Wm1[(size_t)k * 128 + c], acc);
    g[gi * 128 + c] = fmaxf(acc, 0.f);
}

__global__ __launch_bounds__(256) void mlp2_k(const float* __restrict__ g,
                                              const float* __restrict__ Wm2,
                                              const float* __restrict__ bm2,
                                              float* __restrict__ out) {
    int idx = blockIdx.x * 256 + threadIdx.x;
    int gi = idx >> 4, c = idx & 15;
    float acc = bm2[c];
    for (int k = 0; k < 128; ++k) acc = fmaf(g[gi * 128 + k], Wm2[k * 16 + c], acc);
    out[gi * 16 + c] = acc;
}

extern "C" void kernel_launch(void* const* d_in, const int* in_sizes, int n_in,
                              void* d_out, int out_size, void* d_ws, size_t ws_size,
                              hipStream_t stream) {
    const float* x   = (const float*)d_in[0];
    const int*   ei  = (const int*)d_in[1];
    const float* ew  = (const float*)d_in[2];
    const int*   gix = (const int*)d_in[3];
    const float* W1  = (const float*)d_in[4];
    const float* b1  = (const float*)d_in[5];
    const float* W2  = (const float*)d_in[6];
    const float* b2  = (const float*)d_in[7];
    const float* gam = (const float*)d_in[8];
    const float* bet = (const float*)d_in[9];
    const float* bmn = (const float*)d_in[10];
    const float* bvr = (const float*)d_in[11];
    const float* Wm1 = (const float*)d_in[12];
    const float* bm1 = (const float*)d_in[13];
    const float* Wm2 = (const float*)d_in[14];
    const float* bm2 = (const float*)d_in[15];
    float* out = (float*)d_out;

    // workspace layout (4B units):
    // h [NN*U] | aggz [NN*U] | pooled [NG*384] | g [NG*128] |
    // src_s [NE] | w_s [NE] | rowptr [NN+1] | cursor [NN] | hist [NN]
    float* h      = (float*)d_ws;
    float* aggz   = h + (size_t)NN * U;
    float* pooled = aggz + (size_t)NN * U;
    float* gbuf   = pooled + (size_t)NG * (NGIN * U);
    int*   src_s  = (int*)(gbuf + (size_t)NG * 128);
    float* w_s    = (float*)(src_s + NE);
    int*   rowptr = (int*)(w_s + NE);
    int*   cursor = rowptr + (NN + 1);
    int*   hist   = cursor + NN;

    // ---- sort edges by dst (once per launch) ----
    hipMemsetAsync(hist, 0, NN * sizeof(int), stream);
    hist_k<<<(NE + 255) / 256, 256, 0, stream>>>(ei, hist);
    scan_k<<<1, 1024, 0, stream>>>(hist, rowptr);
    hipMemcpyAsync(cursor, rowptr, NN * sizeof(int), hipMemcpyDeviceToDevice, stream);
    bin_k<<<(NE + 255) / 256, 256, 0, stream>>>(ei, ew, cursor, src_s, w_s);

    hipMemsetAsync(pooled, 0, (size_t)NG * (NGIN * U) * sizeof(float), stream);
    for (int i = 0; i < NGIN; ++i) {
        const float* hin = (i == 0) ? x : h;
        // z = 1.5*h + gathered neighbor sum  -> aggz
        gather_k<<<NN / 4, 256, 0, stream>>>(hin, src_s, w_s, rowptr, aggz);
        // z1 = relu(z @ W1 + b1)  (in-place over aggz)
        dense_k<0><<<NN / 32, 256, 0, stream>>>(aggz, W1 + (size_t)i * U * U, b1 + i * U,
                                                nullptr, nullptr, nullptr, nullptr, nullptr,
                                                aggz, nullptr, 0);
        // h = relu(bn(z1 @ W2 + b2)); pooled += h
        dense_k<1><<<NN / 32, 256, 0, stream>>>(aggz, W2 + (size_t)i * U * U, b2 + i * U,
                                                gam + i * U, bet + i * U, bmn + i * U, bvr + i * U,
                                                gix, h, pooled, i * U);
    }
    mlp1_k<<<NG, 128, 0, stream>>>(pooled, Wm1, bm1, gbuf);
    mlp2_k<<<(NG * 16) / 256, 256, 0, stream>>>(gbuf, Wm2, bm2, out);
}

// Round 3
// 1039.614 us; speedup vs baseline: 4.5471x; 1.1684x over previous
//
#include <hip/hip_runtime.h>

#define NN 100000
#define NE 800000
#define NG 128
#define U  128
#define NGIN 3
#define SCAN_CHUNK 2048
#define NB ((NN + SCAN_CHUNK - 1) / SCAN_CHUNK)   // 49 blocks

// ---------------------------------------------------------------------------
// edge sort by dst: histogram -> 3-phase device scan -> bin
// ---------------------------------------------------------------------------
__global__ __launch_bounds__(256) void hist_k(const int* __restrict__ ei,
                                              int* __restrict__ hist) {
    int e = blockIdx.x * 256 + threadIdx.x;
    if (e < NE) atomicAdd(&hist[ei[e]], 1);
}

// phase 1: per-block sums (49 blocks x 256 threads x 8 elems)
__global__ __launch_bounds__(256) void scan1_k(const int* __restrict__ hist,
                                               int* __restrict__ bsum) {
    int t = threadIdx.x;
    int base = blockIdx.x * SCAN_CHUNK + t * 8;
    int s = 0;
#pragma unroll
    for (int j = 0; j < 8; ++j) {
        int i = base + j;
        s += (i < NN) ? hist[i] : 0;
    }
#pragma unroll
    for (int off = 32; off > 0; off >>= 1) s += __shfl_down(s, off);
    __shared__ int ws[4];
    int lane = t & 63, wid = t >> 6;
    if (lane == 0) ws[wid] = s;
    __syncthreads();
    if (t == 0) bsum[blockIdx.x] = ws[0] + ws[1] + ws[2] + ws[3];
}

// phase 2: one wave scans the 49 block sums -> exclusive offsets
__global__ __launch_bounds__(64) void scan2_k(const int* __restrict__ bsum,
                                              int* __restrict__ boff,
                                              int* __restrict__ rowptr) {
    int lane = threadIdx.x;
    int v = (lane < NB) ? bsum[lane] : 0;
    int incl = v;
#pragma unroll
    for (int off = 1; off < 64; off <<= 1) {
        int n = __shfl_up(incl, off);
        if (lane >= off) incl += n;
    }
    if (lane < NB) boff[lane] = incl - v;
    if (lane == 0) rowptr[NN] = NE;
}

// phase 3: local exclusive scan + block offset -> rowptr AND cursor
__global__ __launch_bounds__(256) void scan3_k(const int* __restrict__ hist,
                                               const int* __restrict__ boff,
                                               int* __restrict__ rowptr,
                                               int* __restrict__ cursor) {
    int t = threadIdx.x;
    int base = blockIdx.x * SCAN_CHUNK + t * 8;
    int v[8];
    int s = 0;
#pragma unroll
    for (int j = 0; j < 8; ++j) {
        int i = base + j;
        v[j] = (i < NN) ? hist[i] : 0;
        s += v[j];
    }
    int lane = t & 63, wid = t >> 6;
    int incl = s;
#pragma unroll
    for (int off = 1; off < 64; off <<= 1) {
        int n = __shfl_up(incl, off);
        if (lane >= off) incl += n;
    }
    __shared__ int ws[4];
    if (lane == 63) ws[wid] = incl;
    __syncthreads();
    if (t == 0) {
        int a = 0;
#pragma unroll
        for (int w = 0; w < 4; ++w) { int tmp = ws[w]; ws[w] = a; a += tmp; }
    }
    __syncthreads();
    int run = boff[blockIdx.x] + ws[wid] + (incl - s);
#pragma unroll
    for (int j = 0; j < 8; ++j) {
        int i = base + j;
        if (i < NN) { rowptr[i] = run; cursor[i] = run; }
        run += v[j];
    }
}

__global__ __launch_bounds__(256) void bin_k(const int* __restrict__ ei,
                                             const float* __restrict__ ew,
                                             int* __restrict__ cursor,
                                             int* __restrict__ src_s,
                                             float* __restrict__ w_s) {
    int e = blockIdx.x * 256 + threadIdx.x;
    if (e >= NE) return;
    int d = ei[e];
    int pos = atomicAdd(&cursor[d], 1);
    src_s[pos] = ei[NE + e];
    w_s[pos] = ew[e];
}

// ---------------------------------------------------------------------------
// gather: z[n] = 1.5*h[n] + sum_{e in row n} h[src[e]] * w[e]
// one wave per node, lane owns 2 units
// ---------------------------------------------------------------------------
__global__ __launch_bounds__(256) void gather_k(const float* __restrict__ h,
                                                const int* __restrict__ src_s,
                                                const float* __restrict__ w_s,
                                                const int* __restrict__ rowptr,
                                                float* __restrict__ z) {
    int node = blockIdx.x * 4 + (threadIdx.x >> 6);
    if (node >= NN) return;
    int lane = threadIdx.x & 63;
    int beg = rowptr[node], end = rowptr[node + 1];
    float2 acc = make_float2(0.f, 0.f);
    for (int e = beg; e < end; ++e) {
        int s = src_s[e];
        float w = w_s[e];
        float2 hv = *reinterpret_cast<const float2*>(h + (size_t)s * U + lane * 2);
        acc.x = fmaf(hv.x, w, acc.x);
        acc.y = fmaf(hv.y, w, acc.y);
    }
    float2 hn = *reinterpret_cast<const float2*>(h + (size_t)node * U + lane * 2);
    acc.x = fmaf(1.5f, hn.x, acc.x);
    acc.y = fmaf(1.5f, hn.y, acc.y);
    *reinterpret_cast<float2*>(z + (size_t)node * U + lane * 2) = acc;
}

// ---------------------------------------------------------------------------
// dense: C[row, :] = act(A @ W + b)
// MODE 0: epilogue relu                   -> z1
// MODE 1: epilogue bn+relu + pool-atomic  -> h
// ---------------------------------------------------------------------------
template <int MODE>
__global__ __launch_bounds__(256) void dense_k(const float* __restrict__ A0,
                                               const float* __restrict__ W,
                                               const float* __restrict__ bias,
                                               const float* __restrict__ gamma,
                                               const float* __restrict__ beta,
                                               const float* __restrict__ mean,
                                               const float* __restrict__ var,
                                               const int* __restrict__ gidx,
                                               float* __restrict__ outp,
                                               float* __restrict__ pooled,
                                               int pool_off) {
    __shared__ float sW[32][128];
    __shared__ float sA[32][32];
    const int tid = threadIdx.x;
    const int row0 = blockIdx.x * 32;
    const int rg = tid >> 5;
    const int c0 = (tid & 31) << 2;

    float4 acc[4];
#pragma unroll
    for (int i = 0; i < 4; ++i) acc[i] = make_float4(0.f, 0.f, 0.f, 0.f);

    for (int kc = 0; kc < 4; ++kc) {
        const int k0 = kc * 32;
#pragma unroll
        for (int j = 0; j < 16; ++j) {
            int idx = tid + j * 256;
            int k = idx >> 7, c = idx & 127;
            sW[k][c] = W[(size_t)(k0 + k) * U + c];
        }
#pragma unroll
        for (int j = 0; j < 4; ++j) {
            int idx = tid + j * 256;
            int r = idx >> 5, kk = idx & 31;
            sA[r][kk] = A0[(size_t)(row0 + r) * U + k0 + kk];
        }
        __syncthreads();
#pragma unroll
        for (int kk = 0; kk < 32; kk += 4) {
            float4 w0 = *reinterpret_cast<const float4*>(&sW[kk + 0][c0]);
            float4 w1 = *reinterpret_cast<const float4*>(&sW[kk + 1][c0]);
            float4 w2 = *reinterpret_cast<const float4*>(&sW[kk + 2][c0]);
            float4 w3 = *reinterpret_cast<const float4*>(&sW[kk + 3][c0]);
#pragma unroll
            for (int i = 0; i < 4; ++i) {
                float4 a = *reinterpret_cast<const float4*>(&sA[rg * 4 + i][kk]);
                acc[i].x = fmaf(a.w, w3.x, fmaf(a.z, w2.x, fmaf(a.y, w1.x, fmaf(a.x, w0.x, acc[i].x))));
                acc[i].y = fmaf(a.w, w3.y, fmaf(a.z, w2.y, fmaf(a.y, w1.y, fmaf(a.x, w0.y, acc[i].y))));
                acc[i].z = fmaf(a.w, w3.z, fmaf(a.z, w2.z, fmaf(a.y, w1.z, fmaf(a.x, w0.z, acc[i].z))));
                acc[i].w = fmaf(a.w, w3.w, fmaf(a.z, w2.w, fmaf(a.y, w1.w, fmaf(a.x, w0.w, acc[i].w))));
            }
        }
        __syncthreads();
    }

    float4 b = *reinterpret_cast<const float4*>(&bias[c0]);
    if (MODE == 0) {
#pragma unroll
        for (int i = 0; i < 4; ++i) {
            float4 v;
            v.x = fmaxf(acc[i].x + b.x, 0.f);
            v.y = fmaxf(acc[i].y + b.y, 0.f);
            v.z = fmaxf(acc[i].z + b.z, 0.f);
            v.w = fmaxf(acc[i].w + b.w, 0.f);
            *reinterpret_cast<float4*>(outp + (size_t)(row0 + rg * 4 + i) * U + c0) = v;
        }
    } else {
        float4 m  = *reinterpret_cast<const float4*>(&mean[c0]);
        float4 vv = *reinterpret_cast<const float4*>(&var[c0]);
        float4 g4 = *reinterpret_cast<const float4*>(&gamma[c0]);
        float4 bt = *reinterpret_cast<const float4*>(&beta[c0]);
        float4 scl;
        scl.x = g4.x * rsqrtf(vv.x + 1e-3f);
        scl.y = g4.y * rsqrtf(vv.y + 1e-3f);
        scl.z = g4.z * rsqrtf(vv.z + 1e-3f);
        scl.w = g4.w * rsqrtf(vv.w + 1e-3f);
        float4 hv[4];
#pragma unroll
        for (int i = 0; i < 4; ++i) {
            float4 v;
            v.x = fmaxf((acc[i].x + b.x - m.x) * scl.x + bt.x, 0.f);
            v.y = fmaxf((acc[i].y + b.y - m.y) * scl.y + bt.y, 0.f);
            v.z = fmaxf((acc[i].z + b.z - m.z) * scl.z + bt.z, 0.f);
            v.w = fmaxf((acc[i].w + b.w - m.w) * scl.w + bt.w, 0.f);
            hv[i] = v;
            *reinterpret_cast<float4*>(outp + (size_t)(row0 + rg * 4 + i) * U + c0) = v;
        }
        int r0 = row0 + rg * 4;
        int ga = gidx[r0], gb = gidx[r0 + 3];
        if (ga == gb) {
            float* pp = pooled + (size_t)ga * (NGIN * U) + pool_off + c0;
            unsafeAtomicAdd(pp + 0, hv[0].x + hv[1].x + hv[2].x + hv[3].x);
            unsafeAtomicAdd(pp + 1, hv[0].y + hv[1].y + hv[2].y + hv[3].y);
            unsafeAtomicAdd(pp + 2, hv[0].z + hv[1].z + hv[2].z + hv[3].z);
            unsafeAtomicAdd(pp + 3, hv[0].w + hv[1].w + hv[2].w + hv[3].w);
        } else {
#pragma unroll
            for (int i = 0; i < 4; ++i) {
                float* pp = pooled + (size_t)gidx[r0 + i] * (NGIN * U) + pool_off + c0;
                unsafeAtomicAdd(pp + 0, hv[i].x);
                unsafeAtomicAdd(pp + 1, hv[i].y);
                unsafeAtomicAdd(pp + 2, hv[i].z);
                unsafeAtomicAdd(pp + 3, hv[i].w);
            }
        }
    }
}

// ---------------------------------------------------------------------------
// readout MLPs
// ---------------------------------------------------------------------------
__global__ __launch_bounds__(128) void mlp1_k(const float* __restrict__ pooled,
                                              const float* __restrict__ Wm1,
                                              const float* __restrict__ bm1,
                                              float* __restrict__ g) {
    __shared__ float sp[NGIN * U];
    int gi = blockIdx.x, c = threadIdx.x;
    for (int j = c; j < NGIN * U; j += 128) sp[j] = pooled[(size_t)gi * (NGIN * U) + j];
    __syncthreads();
    float acc = bm1[c];
    for (int k = 0; k < NGIN * U; ++k) acc = fmaf(sp[k], Wm1[(size_t)k * 128 + c], acc);
    g[gi * 128 + c] = fmaxf(acc, 0.f);
}

__global__ __launch_bounds__(256) void mlp2_k(const float* __restrict__ g,
                                              const float* __restrict__ Wm2,
                                              const float* __restrict__ bm2,
                                              float* __restrict__ out) {
    int idx = blockIdx.x * 256 + threadIdx.x;
    int gi = idx >> 4, c = idx & 15;
    float acc = bm2[c];
    for (int k = 0; k < 128; ++k) acc = fmaf(g[gi * 128 + k], Wm2[k * 16 + c], acc);
    out[gi * 16 + c] = acc;
}

extern "C" void kernel_launch(void* const* d_in, const int* in_sizes, int n_in,
                              void* d_out, int out_size, void* d_ws, size_t ws_size,
                              hipStream_t stream) {
    const float* x   = (const float*)d_in[0];
    const int*   ei  = (const int*)d_in[1];
    const float* ew  = (const float*)d_in[2];
    const int*   gix = (const int*)d_in[3];
    const float* W1  = (const float*)d_in[4];
    const float* b1  = (const float*)d_in[5];
    const float* W2  = (const float*)d_in[6];
    const float* b2  = (const float*)d_in[7];
    const float* gam = (const float*)d_in[8];
    const float* bet = (const float*)d_in[9];
    const float* bmn = (const float*)d_in[10];
    const float* bvr = (const float*)d_in[11];
    const float* Wm1 = (const float*)d_in[12];
    const float* bm1 = (const float*)d_in[13];
    const float* Wm2 = (const float*)d_in[14];
    const float* bm2 = (const float*)d_in[15];
    float* out = (float*)d_out;

    // workspace layout (4B units):
    // h [NN*U] | aggz [NN*U] | pooled | g | src_s [NE] | w_s [NE] |
    // rowptr [NN+1] | cursor [NN] | hist [NN] | bsum [NB] | boff [NB]
    float* h      = (float*)d_ws;
    float* aggz   = h + (size_t)NN * U;
    float* pooled = aggz + (size_t)NN * U;
    float* gbuf   = pooled + (size_t)NG * (NGIN * U);
    int*   src_s  = (int*)(gbuf + (size_t)NG * 128);
    float* w_s    = (float*)(src_s + NE);
    int*   rowptr = (int*)(w_s + NE);
    int*   cursor = rowptr + (NN + 1);
    int*   hist   = cursor + NN;
    int*   bsum   = hist + NN;
    int*   boff   = bsum + NB;

    // ---- sort edges by dst (once per launch) ----
    hipMemsetAsync(hist, 0, NN * sizeof(int), stream);
    hist_k<<<(NE + 255) / 256, 256, 0, stream>>>(ei, hist);
    scan1_k<<<NB, 256, 0, stream>>>(hist, bsum);
    scan2_k<<<1, 64, 0, stream>>>(bsum, boff, rowptr);
    scan3_k<<<NB, 256, 0, stream>>>(hist, boff, rowptr, cursor);
    bin_k<<<(NE + 255) / 256, 256, 0, stream>>>(ei, ew, cursor, src_s, w_s);

    hipMemsetAsync(pooled, 0, (size_t)NG * (NGIN * U) * sizeof(float), stream);
    for (int i = 0; i < NGIN; ++i) {
        const float* hin = (i == 0) ? x : h;
        gather_k<<<NN / 4, 256, 0, stream>>>(hin, src_s, w_s, rowptr, aggz);
        dense_k<0><<<NN / 32, 256, 0, stream>>>(aggz, W1 + (size_t)i * U * U, b1 + i * U,
                                                nullptr, nullptr, nullptr, nullptr, nullptr,
                                                aggz, nullptr, 0);
        dense_k<1><<<NN / 32, 256, 0, stream>>>(aggz, W2 + (size_t)i * U * U, b2 + i * U,
                                                gam + i * U, bet + i * U, bmn + i * U, bvr + i * U,
                                                gix, h, pooled, i * U);
    }
    mlp1_k<<<NG, 128, 0, stream>>>(pooled, Wm1, bm1, gbuf);
    mlp2_k<<<(NG * 16) / 256, 256, 0, stream>>>(gbuf, Wm2, bm2, out);
}

// Round 4
// 544.258 us; speedup vs baseline: 8.6857x; 1.9101x over previous
//
#include <hip/hip_runtime.h>

#define NN 100000
#define NE 800000
#define NG 128
#define U  128
#define NGIN 3
#define SCAN_CHUNK 2048
#define NB ((NN + SCAN_CHUNK - 1) / SCAN_CHUNK)   // 49 blocks

typedef short bf16x8 __attribute__((ext_vector_type(8)));
typedef float f32x4 __attribute__((ext_vector_type(4)));

__device__ __forceinline__ unsigned short f2b(float f) {
    union { float f; unsigned u; } v; v.f = f;
    unsigned r = v.u + 0x7FFF + ((v.u >> 16) & 1);   // RNE
    return (unsigned short)(r >> 16);
}
__device__ __forceinline__ float b2f(unsigned short h) {
    union { unsigned u; float f; } v; v.u = ((unsigned)h) << 16;
    return v.f;
}

// ---------------------------------------------------------------------------
// x (fp32) -> hb (bf16)
// ---------------------------------------------------------------------------
__global__ __launch_bounds__(256) void convert_k(const float* __restrict__ x,
                                                 unsigned short* __restrict__ hb) {
    int i = blockIdx.x * 256 + threadIdx.x;          // one float4 per thread
    if (i >= NN * U / 4) return;
    float4 v = reinterpret_cast<const float4*>(x)[i];
    uint2 o;
    o.x = (unsigned)f2b(v.x) | ((unsigned)f2b(v.y) << 16);
    o.y = (unsigned)f2b(v.z) | ((unsigned)f2b(v.w) << 16);
    reinterpret_cast<uint2*>(hb)[i] = o;
}

// ---------------------------------------------------------------------------
// pack W (fp32 [k][c]) into MFMA B-fragment order (bf16):
// frag[((ct*4+ks)*64+lane)*8+j] = W[ks*32+8*(lane>>4)+j][ct*16+(lane&15)]
// block b: layer = b>>1, which = b&1 (0=W1, 1=W2)
// ---------------------------------------------------------------------------
__global__ __launch_bounds__(256) void wfrag_k(const float* __restrict__ W1,
                                               const float* __restrict__ W2,
                                               unsigned short* __restrict__ wfrag) {
    int b = blockIdx.x;
    const float* src = ((b & 1) ? W2 : W1) + (size_t)(b >> 1) * U * U;
    unsigned short* dst = wfrag + (size_t)b * 16384;
    for (int e = threadIdx.x; e < 16384; e += 256) {
        int j = e & 7, lane = (e >> 3) & 63, ks = (e >> 9) & 3, ct = e >> 11;
        int k = ks * 32 + ((lane >> 4) << 3) + j;
        int c = ct * 16 + (lane & 15);
        dst[e] = f2b(src[k * U + c]);
    }
}

// ---------------------------------------------------------------------------
// edge sort by dst: histogram -> 3-phase device scan -> bin
// ---------------------------------------------------------------------------
__global__ __launch_bounds__(256) void hist_k(const int* __restrict__ ei,
                                              int* __restrict__ hist) {
    int e = blockIdx.x * 256 + threadIdx.x;
    if (e < NE) atomicAdd(&hist[ei[e]], 1);
}

__global__ __launch_bounds__(256) void scan1_k(const int* __restrict__ hist,
                                               int* __restrict__ bsum) {
    int t = threadIdx.x;
    int base = blockIdx.x * SCAN_CHUNK + t * 8;
    int s = 0;
#pragma unroll
    for (int j = 0; j < 8; ++j) {
        int i = base + j;
        s += (i < NN) ? hist[i] : 0;
    }
#pragma unroll
    for (int off = 32; off > 0; off >>= 1) s += __shfl_down(s, off);
    __shared__ int ws[4];
    int lane = t & 63, wid = t >> 6;
    if (lane == 0) ws[wid] = s;
    __syncthreads();
    if (t == 0) bsum[blockIdx.x] = ws[0] + ws[1] + ws[2] + ws[3];
}

__global__ __launch_bounds__(64) void scan2_k(const int* __restrict__ bsum,
                                              int* __restrict__ boff,
                                              int* __restrict__ rowptr) {
    int lane = threadIdx.x;
    int v = (lane < NB) ? bsum[lane] : 0;
    int incl = v;
#pragma unroll
    for (int off = 1; off < 64; off <<= 1) {
        int n = __shfl_up(incl, off);
        if (lane >= off) incl += n;
    }
    if (lane < NB) boff[lane] = incl - v;
    if (lane == 0) rowptr[NN] = NE;
}

__global__ __launch_bounds__(256) void scan3_k(const int* __restrict__ hist,
                                               const int* __restrict__ boff,
                                               int* __restrict__ rowptr,
                                               int* __restrict__ cursor) {
    int t = threadIdx.x;
    int base = blockIdx.x * SCAN_CHUNK + t * 8;
    int v[8];
    int s = 0;
#pragma unroll
    for (int j = 0; j < 8; ++j) {
        int i = base + j;
        v[j] = (i < NN) ? hist[i] : 0;
        s += v[j];
    }
    int lane = t & 63, wid = t >> 6;
    int incl = s;
#pragma unroll
    for (int off = 1; off < 64; off <<= 1) {
        int n = __shfl_up(incl, off);
        if (lane >= off) incl += n;
    }
    __shared__ int ws[4];
    if (lane == 63) ws[wid] = incl;
    __syncthreads();
    if (t == 0) {
        int a = 0;
#pragma unroll
        for (int w = 0; w < 4; ++w) { int tmp = ws[w]; ws[w] = a; a += tmp; }
    }
    __syncthreads();
    int run = boff[blockIdx.x] + ws[wid] + (incl - s);
#pragma unroll
    for (int j = 0; j < 8; ++j) {
        int i = base + j;
        if (i < NN) { rowptr[i] = run; cursor[i] = run; }
        run += v[j];
    }
}

__global__ __launch_bounds__(256) void bin_k(const int* __restrict__ ei,
                                             const float* __restrict__ ew,
                                             int* __restrict__ cursor,
                                             int* __restrict__ src_s,
                                             float* __restrict__ w_s) {
    int e = blockIdx.x * 256 + threadIdx.x;
    if (e >= NE) return;
    int d = ei[e];
    int pos = atomicAdd(&cursor[d], 1);
    src_s[pos] = ei[NE + e];
    w_s[pos] = ew[e];
}

// ---------------------------------------------------------------------------
// gather (bf16 h): z[n] = 1.5*h[n] + sum h[src]*w   (fp32 accum, bf16 out)
// one wave per node, lane owns 2 units (one dword)
// ---------------------------------------------------------------------------
__global__ __launch_bounds__(256) void gather_k(const unsigned short* __restrict__ h,
                                                const int* __restrict__ src_s,
                                                const float* __restrict__ w_s,
                                                const int* __restrict__ rowptr,
                                                unsigned short* __restrict__ z) {
    int node = blockIdx.x * 4 + (threadIdx.x >> 6);
    if (node >= NN) return;
    int lane = threadIdx.x & 63;
    const unsigned* hp = reinterpret_cast<const unsigned*>(h);
    int beg = rowptr[node], end = rowptr[node + 1];
    float ax = 0.f, ay = 0.f;
    for (int e = beg; e < end; ++e) {
        int s = src_s[e];
        float w = w_s[e];
        unsigned hv = hp[(size_t)s * 64 + lane];
        ax = fmaf(b2f((unsigned short)(hv & 0xffff)), w, ax);
        ay = fmaf(b2f((unsigned short)(hv >> 16)), w, ay);
    }
    unsigned hn = hp[(size_t)node * 64 + lane];
    ax = fmaf(1.5f, b2f((unsigned short)(hn & 0xffff)), ax);
    ay = fmaf(1.5f, b2f((unsigned short)(hn >> 16)), ay);
    reinterpret_cast<unsigned*>(z)[(size_t)node * 64 + lane] =
        (unsigned)f2b(ax) | ((unsigned)f2b(ay) << 16);
}

// ---------------------------------------------------------------------------
// MFMA dense: C[16-row strip][128] = act(A @ W + b)
// wave-private: 4 A-frags (b128 global), 32 B-frags (L1-resident wfrag), no LDS
// MODE 0: relu -> z1 (bf16)
// MODE 1: bn+relu -> h (bf16) + pooled atomics
// ---------------------------------------------------------------------------
template <int MODE>
__global__ __launch_bounds__(256) void mfma_dense_k(const unsigned short* __restrict__ A,
                                                    const unsigned short* __restrict__ wfrag,
                                                    const float* __restrict__ bias,
                                                    const float* __restrict__ gamma,
                                                    const float* __restrict__ beta,
                                                    const float* __restrict__ mean,
                                                    const float* __restrict__ var,
                                                    const int* __restrict__ gidx,
                                                    unsigned short* __restrict__ outp,
                                                    float* __restrict__ pooled,
                                                    int pool_off) {
    const int lane = threadIdx.x & 63;
    const int wid = threadIdx.x >> 6;
    const int r0 = (blockIdx.x * 4 + wid) * 16;
    if (r0 >= NN) return;   // NN % 16 == 0: strips are all-valid or all-invalid

    // A-frags: lane holds A[r0+(lane&15)][ks*32 + 8*(lane>>4) .. +8]
    bf16x8 a[4];
    const size_t abase = (size_t)(r0 + (lane & 15)) * U + ((lane >> 4) << 3);
#pragma unroll
    for (int ks = 0; ks < 4; ++ks)
        a[ks] = *reinterpret_cast<const bf16x8*>(A + abase + ks * 32);

    f32x4 acc[8];
#pragma unroll
    for (int ct = 0; ct < 8; ++ct) acc[ct] = (f32x4){0.f, 0.f, 0.f, 0.f};

#pragma unroll
    for (int ct = 0; ct < 8; ++ct) {
#pragma unroll
        for (int ks = 0; ks < 4; ++ks) {
            bf16x8 b = *reinterpret_cast<const bf16x8*>(
                wfrag + (((ct * 4 + ks) * 64 + lane) << 3));
            acc[ct] = __builtin_amdgcn_mfma_f32_16x16x32_bf16(a[ks], b, acc[ct], 0, 0, 0);
        }
    }

    // C/D layout: col = ct*16 + (lane&15), row = r0 + (lane>>4)*4 + j
    const int c = lane & 15;
    const int rbase = r0 + ((lane >> 4) << 2);
    if (MODE == 0) {
#pragma unroll
        for (int ct = 0; ct < 8; ++ct) {
            int col = ct * 16 + c;
            float bv = bias[col];
#pragma unroll
            for (int j = 0; j < 4; ++j) {
                float v = fmaxf(acc[ct][j] + bv, 0.f);
                outp[(size_t)(rbase + j) * U + col] = f2b(v);
            }
        }
    } else {
        int ga = gidx[r0], gb = gidx[r0 + 15];
        bool uni = (ga == gb);
#pragma unroll
        for (int ct = 0; ct < 8; ++ct) {
            int col = ct * 16 + c;
            float bv = bias[col];
            float scl = gamma[col] * rsqrtf(var[col] + 1e-3f);
            float mv = mean[col], bt = beta[col];
            float hv[4];
            float psum = 0.f;
#pragma unroll
            for (int j = 0; j < 4; ++j) {
                float v = fmaxf((acc[ct][j] + bv - mv) * scl + bt, 0.f);
                hv[j] = v;
                psum += v;
                outp[(size_t)(rbase + j) * U + col] = f2b(v);
            }
            if (uni) {
                psum += __shfl_xor(psum, 16);
                psum += __shfl_xor(psum, 32);
                if (lane < 16)
                    unsafeAtomicAdd(&pooled[(size_t)ga * (NGIN * U) + pool_off + col], psum);
            } else {
#pragma unroll
                for (int j = 0; j < 4; ++j)
                    unsafeAtomicAdd(&pooled[(size_t)gidx[rbase + j] * (NGIN * U) + pool_off + col], hv[j]);
            }
        }
    }
}

// ---------------------------------------------------------------------------
// readout MLPs (fp32, tiny)
// ---------------------------------------------------------------------------
__global__ __launch_bounds__(128) void mlp1_k(const float* __restrict__ pooled,
                                              const float* __restrict__ Wm1,
                                              const float* __restrict__ bm1,
                                              float* __restrict__ g) {
    __shared__ float sp[NGIN * U];
    int gi = blockIdx.x, c = threadIdx.x;
    for (int j = c; j < NGIN * U; j += 128) sp[j] = pooled[(size_t)gi * (NGIN * U) + j];
    __syncthreads();
    float acc = bm1[c];
    for (int k = 0; k < NGIN * U; ++k) acc = fmaf(sp[k], Wm1[(size_t)k * 128 + c], acc);
    g[gi * 128 + c] = fmaxf(acc, 0.f);
}

__global__ __launch_bounds__(256) void mlp2_k(const float* __restrict__ g,
                                              const float* __restrict__ Wm2,
                                              const float* __restrict__ bm2,
                                              float* __restrict__ out) {
    int idx = blockIdx.x * 256 + threadIdx.x;
    int gi = idx >> 4, c = idx & 15;
    float acc = bm2[c];
    for (int k = 0; k < 128; ++k) acc = fmaf(g[gi * 128 + k], Wm2[k * 16 + c], acc);
    out[gi * 16 + c] = acc;
}

extern "C" void kernel_launch(void* const* d_in, const int* in_sizes, int n_in,
                              void* d_out, int out_size, void* d_ws, size_t ws_size,
                              hipStream_t stream) {
    const float* x   = (const float*)d_in[0];
    const int*   ei  = (const int*)d_in[1];
    const float* ew  = (const float*)d_in[2];
    const int*   gix = (const int*)d_in[3];
    const float* W1  = (const float*)d_in[4];
    const float* b1  = (const float*)d_in[5];
    const float* W2  = (const float*)d_in[6];
    const float* b2  = (const float*)d_in[7];
    const float* gam = (const float*)d_in[8];
    const float* bet = (const float*)d_in[9];
    const float* bmn = (const float*)d_in[10];
    const float* bvr = (const float*)d_in[11];
    const float* Wm1 = (const float*)d_in[12];
    const float* bm1 = (const float*)d_in[13];
    const float* Wm2 = (const float*)d_in[14];
    const float* bm2 = (const float*)d_in[15];
    float* out = (float*)d_out;

    // workspace layout:
    // hb,z,z1: bf16 [NN][128] | pooled f32 | g f32 | wfrag bf16 [6*16384] |
    // src_s [NE] | w_s [NE] | rowptr [NN+1] | cursor [NN] | hist [NN] | bsum | boff
    unsigned short* hb = (unsigned short*)d_ws;
    unsigned short* z  = hb + (size_t)NN * U;
    unsigned short* z1 = z + (size_t)NN * U;
    float* pooled = (float*)(z1 + (size_t)NN * U);
    float* gbuf   = pooled + (size_t)NG * (NGIN * U);
    unsigned short* wfrag = (unsigned short*)(gbuf + (size_t)NG * 128);
    int*   src_s  = (int*)(wfrag + 6 * 16384);
    float* w_s    = (float*)(src_s + NE);
    int*   rowptr = (int*)(w_s + NE);
    int*   cursor = rowptr + (NN + 1);
    int*   hist   = cursor + NN;
    int*   bsum   = hist + NN;
    int*   boff   = bsum + NB;

    // ---- one-time prep ----
    convert_k<<<(NN * U / 4 + 255) / 256, 256, 0, stream>>>(x, hb);
    hipMemsetAsync(hist, 0, NN * sizeof(int), stream);
    hist_k<<<(NE + 255) / 256, 256, 0, stream>>>(ei, hist);
    scan1_k<<<NB, 256, 0, stream>>>(hist, bsum);
    scan2_k<<<1, 64, 0, stream>>>(bsum, boff, rowptr);
    scan3_k<<<NB, 256, 0, stream>>>(hist, boff, rowptr, cursor);
    bin_k<<<(NE + 255) / 256, 256, 0, stream>>>(ei, ew, cursor, src_s, w_s);
    wfrag_k<<<6, 256, 0, stream>>>(W1, W2, wfrag);
    hipMemsetAsync(pooled, 0, (size_t)NG * (NGIN * U) * sizeof(float), stream);

    const int dense_grid = (NN + 63) / 64;   // 64 rows/block (4 waves x 16)
    for (int i = 0; i < NGIN; ++i) {
        gather_k<<<NN / 4, 256, 0, stream>>>(hb, src_s, w_s, rowptr, z);
        mfma_dense_k<0><<<dense_grid, 256, 0, stream>>>(
            z, wfrag + (size_t)(2 * i) * 16384, b1 + i * U,
            nullptr, nullptr, nullptr, nullptr, nullptr, z1, nullptr, 0);
        mfma_dense_k<1><<<dense_grid, 256, 0, stream>>>(
            z1, wfrag + (size_t)(2 * i + 1) * 16384, b2 + i * U,
            gam + i * U, bet + i * U, bmn + i * U, bvr + i * U,
            gix, hb, pooled, i * U);
    }
    mlp1_k<<<NG, 128, 0, stream>>>(pooled, Wm1, bm1, gbuf);
    mlp2_k<<<(NG * 16) / 256, 256, 0, stream>>>(gbuf, Wm2, bm2, out);
}

// Round 5
// 407.492 us; speedup vs baseline: 11.6008x; 1.3356x over previous
//
#include <hip/hip_runtime.h>

#define NN 100000
#define NE 800000
#define NG 128
#define U  128
#define NGIN 3
#define SCAN_CHUNK 2048
#define NB ((NN + SCAN_CHUNK - 1) / SCAN_CHUNK)   // 49 blocks

typedef short bf16x8 __attribute__((ext_vector_type(8)));
typedef float f32x4 __attribute__((ext_vector_type(4)));

__device__ __forceinline__ unsigned short f2b(float f) {
    union { float f; unsigned u; } v; v.f = f;
    unsigned r = v.u + 0x7FFF + ((v.u >> 16) & 1);   // RNE
    return (unsigned short)(r >> 16);
}
__device__ __forceinline__ float b2f(unsigned short h) {
    union { unsigned u; float f; } v; v.u = ((unsigned)h) << 16;
    return v.f;
}
__device__ __forceinline__ float blo(unsigned u) {
    union { unsigned u; float f; } v; v.u = u << 16; return v.f;
}
__device__ __forceinline__ float bhi(unsigned u) {
    union { unsigned u; float f; } v; v.u = u & 0xffff0000u; return v.f;
}

// ---------------------------------------------------------------------------
// x (fp32) -> hb (bf16)
// ---------------------------------------------------------------------------
__global__ __launch_bounds__(256) void convert_k(const float* __restrict__ x,
                                                 unsigned short* __restrict__ hb) {
    int i = blockIdx.x * 256 + threadIdx.x;
    if (i >= NN * U / 4) return;
    float4 v = reinterpret_cast<const float4*>(x)[i];
    uint2 o;
    o.x = (unsigned)f2b(v.x) | ((unsigned)f2b(v.y) << 16);
    o.y = (unsigned)f2b(v.z) | ((unsigned)f2b(v.w) << 16);
    reinterpret_cast<uint2*>(hb)[i] = o;
}

// ---------------------------------------------------------------------------
// pack W (fp32 [k][c]) into MFMA B-fragment order (bf16)
// ---------------------------------------------------------------------------
__global__ __launch_bounds__(256) void wfrag_k(const float* __restrict__ W1,
                                               const float* __restrict__ W2,
                                               unsigned short* __restrict__ wfrag) {
    int b = blockIdx.x;
    const float* src = ((b & 1) ? W2 : W1) + (size_t)(b >> 1) * U * U;
    unsigned short* dst = wfrag + (size_t)b * 16384;
    for (int e = threadIdx.x; e < 16384; e += 256) {
        int j = e & 7, lane = (e >> 3) & 63, ks = (e >> 9) & 3, ct = e >> 11;
        int k = ks * 32 + ((lane >> 4) << 3) + j;
        int c = ct * 16 + (lane & 15);
        dst[e] = f2b(src[k * U + c]);
    }
}

// ---------------------------------------------------------------------------
// edge sort by dst: histogram -> 3-phase device scan -> bin
// ---------------------------------------------------------------------------
__global__ __launch_bounds__(256) void hist_k(const int* __restrict__ ei,
                                              int* __restrict__ hist) {
    int e = blockIdx.x * 256 + threadIdx.x;
    if (e < NE) atomicAdd(&hist[ei[e]], 1);
}

__global__ __launch_bounds__(256) void scan1_k(const int* __restrict__ hist,
                                               int* __restrict__ bsum) {
    int t = threadIdx.x;
    int base = blockIdx.x * SCAN_CHUNK + t * 8;
    int s = 0;
#pragma unroll
    for (int j = 0; j < 8; ++j) {
        int i = base + j;
        s += (i < NN) ? hist[i] : 0;
    }
#pragma unroll
    for (int off = 32; off > 0; off >>= 1) s += __shfl_down(s, off);
    __shared__ int ws[4];
    int lane = t & 63, wid = t >> 6;
    if (lane == 0) ws[wid] = s;
    __syncthreads();
    if (t == 0) bsum[blockIdx.x] = ws[0] + ws[1] + ws[2] + ws[3];
}

__global__ __launch_bounds__(64) void scan2_k(const int* __restrict__ bsum,
                                              int* __restrict__ boff,
                                              int* __restrict__ rowptr) {
    int lane = threadIdx.x;
    int v = (lane < NB) ? bsum[lane] : 0;
    int incl = v;
#pragma unroll
    for (int off = 1; off < 64; off <<= 1) {
        int n = __shfl_up(incl, off);
        if (lane >= off) incl += n;
    }
    if (lane < NB) boff[lane] = incl - v;
    if (lane == 0) rowptr[NN] = NE;
}

__global__ __launch_bounds__(256) void scan3_k(const int* __restrict__ hist,
                                               const int* __restrict__ boff,
                                               int* __restrict__ rowptr,
                                               int* __restrict__ cursor) {
    int t = threadIdx.x;
    int base = blockIdx.x * SCAN_CHUNK + t * 8;
    int v[8];
    int s = 0;
#pragma unroll
    for (int j = 0; j < 8; ++j) {
        int i = base + j;
        v[j] = (i < NN) ? hist[i] : 0;
        s += v[j];
    }
    int lane = t & 63, wid = t >> 6;
    int incl = s;
#pragma unroll
    for (int off = 1; off < 64; off <<= 1) {
        int n = __shfl_up(incl, off);
        if (lane >= off) incl += n;
    }
    __shared__ int ws[4];
    if (lane == 63) ws[wid] = incl;
    __syncthreads();
    if (t == 0) {
        int a = 0;
#pragma unroll
        for (int w = 0; w < 4; ++w) { int tmp = ws[w]; ws[w] = a; a += tmp; }
    }
    __syncthreads();
    int run = boff[blockIdx.x] + ws[wid] + (incl - s);
#pragma unroll
    for (int j = 0; j < 8; ++j) {
        int i = base + j;
        if (i < NN) { rowptr[i] = run; cursor[i] = run; }
        run += v[j];
    }
}

__global__ __launch_bounds__(256) void bin_k(const int* __restrict__ ei,
                                             const float* __restrict__ ew,
                                             int* __restrict__ cursor,
                                             int* __restrict__ src_s,
                                             float* __restrict__ w_s) {
    int e = blockIdx.x * 256 + threadIdx.x;
    if (e >= NE) return;
    int d = ei[e];
    int pos = atomicAdd(&cursor[d], 1);
    src_s[pos] = ei[NE + e];
    w_s[pos] = ew[e];
}

// ---------------------------------------------------------------------------
// gather v2: z[n] = 1.5*h[n] + sum h[src]*w
// wave per node; edge (src,w) pre-loaded vector-wide, shfl-broadcast;
// edges unrolled x4 with independent accumulators (4 row loads in flight)
// ---------------------------------------------------------------------------
__global__ __launch_bounds__(256) void gather_k(const unsigned short* __restrict__ h,
                                                const int* __restrict__ src_s,
                                                const float* __restrict__ w_s,
                                                const int* __restrict__ rowptr,
                                                unsigned short* __restrict__ z) {
    int node = blockIdx.x * 4 + (threadIdx.x >> 6);
    if (node >= NN) return;
    int lane = threadIdx.x & 63;
    const unsigned* hp = reinterpret_cast<const unsigned*>(h);
    int beg = rowptr[node], end = rowptr[node + 1];

    float ax0 = 0.f, ay0 = 0.f, ax1 = 0.f, ay1 = 0.f;
    float ax2 = 0.f, ay2 = 0.f, ax3 = 0.f, ay3 = 0.f;

    for (int cb = beg; cb < end; cb += 64) {
        int n = min(end - cb, 64);
        int sv = 0; float wv = 0.f;            // lanes >= n hold (0, 0.0) pads
        if (lane < n) { sv = src_s[cb + lane]; wv = w_s[cb + lane]; }
        for (int i = 0; i < n; i += 4) {       // groups of 4; pads contribute 0
            int   s0 = __shfl(sv, i),     s1 = __shfl(sv, i + 1);
            int   s2 = __shfl(sv, i + 2), s3 = __shfl(sv, i + 3);
            float w0 = __shfl(wv, i),     w1 = __shfl(wv, i + 1);
            float w2 = __shfl(wv, i + 2), w3 = __shfl(wv, i + 3);
            unsigned h0 = hp[(size_t)s0 * 64 + lane];
            unsigned h1 = hp[(size_t)s1 * 64 + lane];
            unsigned h2 = hp[(size_t)s2 * 64 + lane];
            unsigned h3 = hp[(size_t)s3 * 64 + lane];
            ax0 = fmaf(blo(h0), w0, ax0); ay0 = fmaf(bhi(h0), w0, ay0);
            ax1 = fmaf(blo(h1), w1, ax1); ay1 = fmaf(bhi(h1), w1, ay1);
            ax2 = fmaf(blo(h2), w2, ax2); ay2 = fmaf(bhi(h2), w2, ay2);
            ax3 = fmaf(blo(h3), w3, ax3); ay3 = fmaf(bhi(h3), w3, ay3);
        }
    }
    float ax = (ax0 + ax1) + (ax2 + ax3);
    float ay = (ay0 + ay1) + (ay2 + ay3);
    unsigned hn = hp[(size_t)node * 64 + lane];
    ax = fmaf(1.5f, blo(hn), ax);
    ay = fmaf(1.5f, bhi(hn), ay);
    // note: bhi gives value*1 with low bits zeroed; f2b re-rounds — fine.
    reinterpret_cast<unsigned*>(z)[(size_t)node * 64 + lane] =
        (unsigned)f2b(ax) | ((unsigned)f2b(ay) << 16);
}

// ---------------------------------------------------------------------------
// MFMA dense: C[16-row strip][128] = act(A @ W + b)
// MODE 0: relu -> z1 (bf16)
// MODE 1: bn+relu -> h (bf16) + pooled atomics
// ---------------------------------------------------------------------------
template <int MODE>
__global__ __launch_bounds__(256) void mfma_dense_k(const unsigned short* __restrict__ A,
                                                    const unsigned short* __restrict__ wfrag,
                                                    const float* __restrict__ bias,
                                                    const float* __restrict__ gamma,
                                                    const float* __restrict__ beta,
                                                    const float* __restrict__ mean,
                                                    const float* __restrict__ var,
                                                    const int* __restrict__ gidx,
                                                    unsigned short* __restrict__ outp,
                                                    float* __restrict__ pooled,
                                                    int pool_off) {
    const int lane = threadIdx.x & 63;
    const int wid = threadIdx.x >> 6;
    const int r0 = (blockIdx.x * 4 + wid) * 16;
    if (r0 >= NN) return;

    bf16x8 a[4];
    const size_t abase = (size_t)(r0 + (lane & 15)) * U + ((lane >> 4) << 3);
#pragma unroll
    for (int ks = 0; ks < 4; ++ks)
        a[ks] = *reinterpret_cast<const bf16x8*>(A + abase + ks * 32);

    f32x4 acc[8];
#pragma unroll
    for (int ct = 0; ct < 8; ++ct) acc[ct] = (f32x4){0.f, 0.f, 0.f, 0.f};

#pragma unroll
    for (int ct = 0; ct < 8; ++ct) {
#pragma unroll
        for (int ks = 0; ks < 4; ++ks) {
            bf16x8 b = *reinterpret_cast<const bf16x8*>(
                wfrag + (((ct * 4 + ks) * 64 + lane) << 3));
            acc[ct] = __builtin_amdgcn_mfma_f32_16x16x32_bf16(a[ks], b, acc[ct], 0, 0, 0);
        }
    }

    const int c = lane & 15;
    const int rbase = r0 + ((lane >> 4) << 2);
    if (MODE == 0) {
#pragma unroll
        for (int ct = 0; ct < 8; ++ct) {
            int col = ct * 16 + c;
            float bv = bias[col];
#pragma unroll
            for (int j = 0; j < 4; ++j) {
                float v = fmaxf(acc[ct][j] + bv, 0.f);
                outp[(size_t)(rbase + j) * U + col] = f2b(v);
            }
        }
    } else {
        int ga = gidx[r0], gb = gidx[r0 + 15];
        bool uni = (ga == gb);
#pragma unroll
        for (int ct = 0; ct < 8; ++ct) {
            int col = ct * 16 + c;
            float bv = bias[col];
            float scl = gamma[col] * rsqrtf(var[col] + 1e-3f);
            float mv = mean[col], bt = beta[col];
            float hv[4];
            float psum = 0.f;
#pragma unroll
            for (int j = 0; j < 4; ++j) {
                float v = fmaxf((acc[ct][j] + bv - mv) * scl + bt, 0.f);
                hv[j] = v;
                psum += v;
                outp[(size_t)(rbase + j) * U + col] = f2b(v);
            }
            if (uni) {
                psum += __shfl_xor(psum, 16);
                psum += __shfl_xor(psum, 32);
                if (lane < 16)
                    unsafeAtomicAdd(&pooled[(size_t)ga * (NGIN * U) + pool_off + col], psum);
            } else {
#pragma unroll
                for (int j = 0; j < 4; ++j)
                    unsafeAtomicAdd(&pooled[(size_t)gidx[rbase + j] * (NGIN * U) + pool_off + col], hv[j]);
            }
        }
    }
}

// ---------------------------------------------------------------------------
// readout MLPs (fp32, tiny)
// ---------------------------------------------------------------------------
__global__ __launch_bounds__(128) void mlp1_k(const float* __restrict__ pooled,
                                              const float* __restrict__ Wm1,
                                              const float* __restrict__ bm1,
                                              float* __restrict__ g) {
    __shared__ float sp[NGIN * U];
    int gi = blockIdx.x, c = threadIdx.x;
    for (int j = c; j < NGIN * U; j += 128) sp[j] = pooled[(size_t)gi * (NGIN * U) + j];
    __syncthreads();
    float acc = bm1[c];
    for (int k = 0; k < NGIN * U; ++k) acc = fmaf(sp[k], Wm1[(size_t)k * 128 + c], acc);
    g[gi * 128 + c] = fmaxf(acc, 0.f);
}

__global__ __launch_bounds__(256) void mlp2_k(const float* __restrict__ g,
                                              const float* __restrict__ Wm2,
                                              const float* __restrict__ bm2,
                                              float* __restrict__ out) {
    int idx = blockIdx.x * 256 + threadIdx.x;
    int gi = idx >> 4, c = idx & 15;
    float acc = bm2[c];
    for (int k = 0; k < 128; ++k) acc = fmaf(g[gi * 128 + k], Wm2[k * 16 + c], acc);
    out[gi * 16 + c] = acc;
}

extern "C" void kernel_launch(void* const* d_in, const int* in_sizes, int n_in,
                              void* d_out, int out_size, void* d_ws, size_t ws_size,
                              hipStream_t stream) {
    const float* x   = (const float*)d_in[0];
    const int*   ei  = (const int*)d_in[1];
    const float* ew  = (const float*)d_in[2];
    const int*   gix = (const int*)d_in[3];
    const float* W1  = (const float*)d_in[4];
    const float* b1  = (const float*)d_in[5];
    const float* W2  = (const float*)d_in[6];
    const float* b2  = (const float*)d_in[7];
    const float* gam = (const float*)d_in[8];
    const float* bet = (const float*)d_in[9];
    const float* bmn = (const float*)d_in[10];
    const float* bvr = (const float*)d_in[11];
    const float* Wm1 = (const float*)d_in[12];
    const float* bm1 = (const float*)d_in[13];
    const float* Wm2 = (const float*)d_in[14];
    const float* bm2 = (const float*)d_in[15];
    float* out = (float*)d_out;

    unsigned short* hb = (unsigned short*)d_ws;
    unsigned short* z  = hb + (size_t)NN * U;
    unsigned short* z1 = z + (size_t)NN * U;
    float* pooled = (float*)(z1 + (size_t)NN * U);
    float* gbuf   = pooled + (size_t)NG * (NGIN * U);
    unsigned short* wfrag = (unsigned short*)(gbuf + (size_t)NG * 128);
    int*   src_s  = (int*)(wfrag + 6 * 16384);
    float* w_s    = (float*)(src_s + NE);
    int*   rowptr = (int*)(w_s + NE);
    int*   cursor = rowptr + (NN + 1);
    int*   hist   = cursor + NN;
    int*   bsum   = hist + NN;
    int*   boff   = bsum + NB;

    convert_k<<<(NN * U / 4 + 255) / 256, 256, 0, stream>>>(x, hb);
    hipMemsetAsync(hist, 0, NN * sizeof(int), stream);
    hist_k<<<(NE + 255) / 256, 256, 0, stream>>>(ei, hist);
    scan1_k<<<NB, 256, 0, stream>>>(hist, bsum);
    scan2_k<<<1, 64, 0, stream>>>(bsum, boff, rowptr);
    scan3_k<<<NB, 256, 0, stream>>>(hist, boff, rowptr, cursor);
    bin_k<<<(NE + 255) / 256, 256, 0, stream>>>(ei, ew, cursor, src_s, w_s);
    wfrag_k<<<6, 256, 0, stream>>>(W1, W2, wfrag);
    hipMemsetAsync(pooled, 0, (size_t)NG * (NGIN * U) * sizeof(float), stream);

    const int dense_grid = (NN + 63) / 64;
    for (int i = 0; i < NGIN; ++i) {
        gather_k<<<NN / 4, 256, 0, stream>>>(hb, src_s, w_s, rowptr, z);
        mfma_dense_k<0><<<dense_grid, 256, 0, stream>>>(
            z, wfrag + (size_t)(2 * i) * 16384, b1 + i * U,
            nullptr, nullptr, nullptr, nullptr, nullptr, z1, nullptr, 0);
        mfma_dense_k<1><<<dense_grid, 256, 0, stream>>>(
            z1, wfrag + (size_t)(2 * i + 1) * 16384, b2 + i * U,
            gam + i * U, bet + i * U, bmn + i * U, bvr + i * U,
            gix, hb, pooled, i * U);
    }
    mlp1_k<<<NG, 128, 0, stream>>>(pooled, Wm1, bm1, gbuf);
    mlp2_k<<<(NG * 16) / 256, 256, 0, stream>>>(gbuf, Wm2, bm2, out);
}

// Round 6
// 383.430 us; speedup vs baseline: 12.3288x; 1.0628x over previous
//
#include <hip/hip_runtime.h>

#define NN 100000
#define NE 800000
#define NG 128
#define U  128
#define NGIN 3
#define SCAN_CHUNK 2048
#define NB ((NN + SCAN_CHUNK - 1) / SCAN_CHUNK)   // 49 blocks

typedef short bf16x8 __attribute__((ext_vector_type(8)));
typedef float f32x4 __attribute__((ext_vector_type(4)));

__device__ __forceinline__ unsigned short f2b(float f) {
    union { float f; unsigned u; } v; v.f = f;
    unsigned r = v.u + 0x7FFF + ((v.u >> 16) & 1);   // RNE
    return (unsigned short)(r >> 16);
}
__device__ __forceinline__ float blo(unsigned u) {
    union { unsigned u; float f; } v; v.u = u << 16; return v.f;
}
__device__ __forceinline__ float bhi(unsigned u) {
    union { unsigned u; float f; } v; v.u = u & 0xffff0000u; return v.f;
}

// ---------------------------------------------------------------------------
// x (fp32) -> hb (bf16)
// ---------------------------------------------------------------------------
__global__ __launch_bounds__(256) void convert_k(const float* __restrict__ x,
                                                 unsigned short* __restrict__ hb) {
    int i = blockIdx.x * 256 + threadIdx.x;
    if (i >= NN * U / 4) return;
    float4 v = reinterpret_cast<const float4*>(x)[i];
    uint2 o;
    o.x = (unsigned)f2b(v.x) | ((unsigned)f2b(v.y) << 16);
    o.y = (unsigned)f2b(v.z) | ((unsigned)f2b(v.w) << 16);
    reinterpret_cast<uint2*>(hb)[i] = o;
}

// ---------------------------------------------------------------------------
// pack W (fp32 [k][c]) into MFMA B-fragment order (bf16)
// frag[((ct*4+ks)*64+lane)*8+j] = W[ks*32+8*(lane>>4)+j][ct*16+(lane&15)]
// ---------------------------------------------------------------------------
__global__ __launch_bounds__(256) void wfrag_k(const float* __restrict__ W1,
                                               const float* __restrict__ W2,
                                               unsigned short* __restrict__ wfrag) {
    int b = blockIdx.x;
    const float* src = ((b & 1) ? W2 : W1) + (size_t)(b >> 1) * U * U;
    unsigned short* dst = wfrag + (size_t)b * 16384;
    for (int e = threadIdx.x; e < 16384; e += 256) {
        int j = e & 7, lane = (e >> 3) & 63, ks = (e >> 9) & 3, ct = e >> 11;
        int k = ks * 32 + ((lane >> 4) << 3) + j;
        int c = ct * 16 + (lane & 15);
        dst[e] = f2b(src[k * U + c]);
    }
}

// ---------------------------------------------------------------------------
// edge sort by dst: histogram -> 3-phase device scan -> bin
// ---------------------------------------------------------------------------
__global__ __launch_bounds__(256) void hist_k(const int* __restrict__ ei,
                                              int* __restrict__ hist) {
    int e = blockIdx.x * 256 + threadIdx.x;
    if (e < NE) atomicAdd(&hist[ei[e]], 1);
}

__global__ __launch_bounds__(256) void scan1_k(const int* __restrict__ hist,
                                               int* __restrict__ bsum) {
    int t = threadIdx.x;
    int base = blockIdx.x * SCAN_CHUNK + t * 8;
    int s = 0;
#pragma unroll
    for (int j = 0; j < 8; ++j) {
        int i = base + j;
        s += (i < NN) ? hist[i] : 0;
    }
#pragma unroll
    for (int off = 32; off > 0; off >>= 1) s += __shfl_down(s, off);
    __shared__ int ws[4];
    int lane = t & 63, wid = t >> 6;
    if (lane == 0) ws[wid] = s;
    __syncthreads();
    if (t == 0) bsum[blockIdx.x] = ws[0] + ws[1] + ws[2] + ws[3];
}

__global__ __launch_bounds__(64) void scan2_k(const int* __restrict__ bsum,
                                              int* __restrict__ boff,
                                              int* __restrict__ rowptr) {
    int lane = threadIdx.x;
    int v = (lane < NB) ? bsum[lane] : 0;
    int incl = v;
#pragma unroll
    for (int off = 1; off < 64; off <<= 1) {
        int n = __shfl_up(incl, off);
        if (lane >= off) incl += n;
    }
    if (lane < NB) boff[lane] = incl - v;
    if (lane == 0) rowptr[NN] = NE;
}

__global__ __launch_bounds__(256) void scan3_k(const int* __restrict__ hist,
                                               const int* __restrict__ boff,
                                               int* __restrict__ rowptr,
                                               int* __restrict__ cursor) {
    int t = threadIdx.x;
    int base = blockIdx.x * SCAN_CHUNK + t * 8;
    int v[8];
    int s = 0;
#pragma unroll
    for (int j = 0; j < 8; ++j) {
        int i = base + j;
        v[j] = (i < NN) ? hist[i] : 0;
        s += v[j];
    }
    int lane = t & 63, wid = t >> 6;
    int incl = s;
#pragma unroll
    for (int off = 1; off < 64; off <<= 1) {
        int n = __shfl_up(incl, off);
        if (lane >= off) incl += n;
    }
    __shared__ int ws[4];
    if (lane == 63) ws[wid] = incl;
    __syncthreads();
    if (t == 0) {
        int a = 0;
#pragma unroll
        for (int w = 0; w < 4; ++w) { int tmp = ws[w]; ws[w] = a; a += tmp; }
    }
    __syncthreads();
    int run = boff[blockIdx.x] + ws[wid] + (incl - s);
#pragma unroll
    for (int j = 0; j < 8; ++j) {
        int i = base + j;
        if (i < NN) { rowptr[i] = run; cursor[i] = run; }
        run += v[j];
    }
}

// single 8B (src, w) record per edge: one dirty line per bin instead of two
__global__ __launch_bounds__(256) void bin_k(const int* __restrict__ ei,
                                             const float* __restrict__ ew,
                                             int* __restrict__ cursor,
                                             uint2* __restrict__ euv) {
    int e = blockIdx.x * 256 + threadIdx.x;
    if (e >= NE) return;
    int d = ei[e];
    int pos = atomicAdd(&cursor[d], 1);
    uint2 r;
    r.x = (unsigned)ei[NE + e];
    r.y = __float_as_uint(ew[e]);
    euv[pos] = r;
}

// ---------------------------------------------------------------------------
// gather: z[n] = 1.5*h[n] + sum h[src]*w
// wave per node; (src,w) pre-loaded vector-wide as uint2, shfl-broadcast;
// edges unrolled x4 with independent accumulators
// ---------------------------------------------------------------------------
__global__ __launch_bounds__(256) void gather_k(const unsigned short* __restrict__ h,
                                                const uint2* __restrict__ euv,
                                                const int* __restrict__ rowptr,
                                                unsigned short* __restrict__ z) {
    int node = blockIdx.x * 4 + (threadIdx.x >> 6);
    if (node >= NN) return;
    int lane = threadIdx.x & 63;
    const unsigned* hp = reinterpret_cast<const unsigned*>(h);
    int beg = rowptr[node], end = rowptr[node + 1];

    float ax0 = 0.f, ay0 = 0.f, ax1 = 0.f, ay1 = 0.f;
    float ax2 = 0.f, ay2 = 0.f, ax3 = 0.f, ay3 = 0.f;

    for (int cb = beg; cb < end; cb += 64) {
        int n = min(end - cb, 64);
        int sv = 0; float wv = 0.f;            // pad lanes: (0, 0.0)
        if (lane < n) {
            uint2 ev = euv[cb + lane];
            sv = (int)ev.x;
            wv = __uint_as_float(ev.y);
        }
        for (int i = 0; i < n; i += 4) {
            int   s0 = __shfl(sv, i),     s1 = __shfl(sv, i + 1);
            int   s2 = __shfl(sv, i + 2), s3 = __shfl(sv, i + 3);
            float w0 = __shfl(wv, i),     w1 = __shfl(wv, i + 1);
            float w2 = __shfl(wv, i + 2), w3 = __shfl(wv, i + 3);
            unsigned h0 = hp[(size_t)s0 * 64 + lane];
            unsigned h1 = hp[(size_t)s1 * 64 + lane];
            unsigned h2 = hp[(size_t)s2 * 64 + lane];
            unsigned h3 = hp[(size_t)s3 * 64 + lane];
            ax0 = fmaf(blo(h0), w0, ax0); ay0 = fmaf(bhi(h0), w0, ay0);
            ax1 = fmaf(blo(h1), w1, ax1); ay1 = fmaf(bhi(h1), w1, ay1);
            ax2 = fmaf(blo(h2), w2, ax2); ay2 = fmaf(bhi(h2), w2, ay2);
            ax3 = fmaf(blo(h3), w3, ax3); ay3 = fmaf(bhi(h3), w3, ay3);
        }
    }
    float ax = (ax0 + ax1) + (ax2 + ax3);
    float ay = (ay0 + ay1) + (ay2 + ay3);
    unsigned hn = hp[(size_t)node * 64 + lane];
    ax = fmaf(1.5f, blo(hn), ax);
    ay = fmaf(1.5f, bhi(hn), ay);
    reinterpret_cast<unsigned*>(z)[(size_t)node * 64 + lane] =
        (unsigned)f2b(ax) | ((unsigned)f2b(ay) << 16);
}

// ---------------------------------------------------------------------------
// fused per-layer dense: h = bn(relu(z@W1+b1)@W2+b2), relu, + pooled atomics
// wave owns a 16-row strip; z1 passes through wave-private LDS tile in
// chunk-major layout [chunk=col/8][row][8 bf16]:
//   writes 2-way bank aliased (free), ds_read_b128 reads conflict-free
// ---------------------------------------------------------------------------
__global__ __launch_bounds__(256) void fused_dense_k(const unsigned short* __restrict__ A,
                                                     const unsigned short* __restrict__ wf1,
                                                     const unsigned short* __restrict__ wf2,
                                                     const float* __restrict__ bias1,
                                                     const float* __restrict__ bias2,
                                                     const float* __restrict__ gamma,
                                                     const float* __restrict__ beta,
                                                     const float* __restrict__ mean,
                                                     const float* __restrict__ var,
                                                     const int* __restrict__ gidx,
                                                     unsigned short* __restrict__ outp,
                                                     float* __restrict__ pooled,
                                                     int pool_off) {
    __shared__ unsigned short lds[4 * 2048];   // 4 waves x 4KB
    const int lane = threadIdx.x & 63;
    const int wid = threadIdx.x >> 6;
    const int r0 = (blockIdx.x * 4 + wid) * 16;
    const bool valid = (r0 < NN);
    const int rr = valid ? r0 : 0;             // clamped for safe addressing
    unsigned short* myl = lds + wid * 2048;

    const int c = lane & 15;
    const int g = lane >> 4;

    // ---- matmul 1: z1 = relu(A @ W1 + b1) ----
    bf16x8 a[4];
    const size_t abase = (size_t)(rr + c) * U + (g << 3);
#pragma unroll
    for (int ks = 0; ks < 4; ++ks)
        a[ks] = *reinterpret_cast<const bf16x8*>(A + abase + ks * 32);

    f32x4 acc1[8];
#pragma unroll
    for (int ct = 0; ct < 8; ++ct) acc1[ct] = (f32x4){0.f, 0.f, 0.f, 0.f};
#pragma unroll
    for (int ct = 0; ct < 8; ++ct)
#pragma unroll
        for (int ks = 0; ks < 4; ++ks) {
            bf16x8 b = *reinterpret_cast<const bf16x8*>(
                wf1 + (((ct * 4 + ks) * 64 + lane) << 3));
            acc1[ct] = __builtin_amdgcn_mfma_f32_16x16x32_bf16(a[ks], b, acc1[ct], 0, 0, 0);
        }

    // epilogue 1 -> LDS (chunk-major): idx = chunk*128 + row*8 + (col&7)
#pragma unroll
    for (int ct = 0; ct < 8; ++ct) {
        int col = ct * 16 + c;
        float bv = bias1[col];
        int chunk = col >> 3, within = col & 7;
#pragma unroll
        for (int j = 0; j < 4; ++j) {
            int row = (g << 2) + j;
            float v = fmaxf(acc1[ct][j] + bv, 0.f);
            myl[chunk * 128 + row * 8 + within] = f2b(v);
        }
    }
    __syncthreads();

    // ---- matmul 2: A2-frags from LDS (conflict-free b128) ----
    bf16x8 a2[4];
#pragma unroll
    for (int ks = 0; ks < 4; ++ks)
        a2[ks] = *reinterpret_cast<const bf16x8*>(myl + (ks * 4 + g) * 128 + c * 8);

    f32x4 acc2[8];
#pragma unroll
    for (int ct = 0; ct < 8; ++ct) acc2[ct] = (f32x4){0.f, 0.f, 0.f, 0.f};
#pragma unroll
    for (int ct = 0; ct < 8; ++ct)
#pragma unroll
        for (int ks = 0; ks < 4; ++ks) {
            bf16x8 b = *reinterpret_cast<const bf16x8*>(
                wf2 + (((ct * 4 + ks) * 64 + lane) << 3));
            acc2[ct] = __builtin_amdgcn_mfma_f32_16x16x32_bf16(a2[ks], b, acc2[ct], 0, 0, 0);
        }

    // ---- epilogue 2: bn + relu -> outp, pooled atomics ----
    const int rbase = rr + (g << 2);
    int ga = gidx[rr], gb = gidx[rr + 15];
    bool uni = (ga == gb);
#pragma unroll
    for (int ct = 0; ct < 8; ++ct) {
        int col = ct * 16 + c;
        float bv = bias2[col];
        float scl = gamma[col] * rsqrtf(var[col] + 1e-3f);
        float mv = mean[col], bt = beta[col];
        float hv[4];
        float psum = 0.f;
#pragma unroll
        for (int j = 0; j < 4; ++j) {
            float v = fmaxf((acc2[ct][j] + bv - mv) * scl + bt, 0.f);
            hv[j] = v;
            psum += v;
            if (valid) outp[(size_t)(rbase + j) * U + col] = f2b(v);
        }
        if (uni) {
            psum += __shfl_xor(psum, 16);
            psum += __shfl_xor(psum, 32);
            if (valid && lane < 16)
                unsafeAtomicAdd(&pooled[(size_t)ga * (NGIN * U) + pool_off + col], psum);
        } else if (valid) {
#pragma unroll
            for (int j = 0; j < 4; ++j)
                unsafeAtomicAdd(&pooled[(size_t)gidx[rbase + j] * (NGIN * U) + pool_off + col], hv[j]);
        }
    }
}

// ---------------------------------------------------------------------------
// readout MLPs (fp32, tiny)
// ---------------------------------------------------------------------------
__global__ __launch_bounds__(128) void mlp1_k(const float* __restrict__ pooled,
                                              const float* __restrict__ Wm1,
                                              const float* __restrict__ bm1,
                                              float* __restrict__ g) {
    __shared__ float sp[NGIN * U];
    int gi = blockIdx.x, c = threadIdx.x;
    for (int j = c; j < NGIN * U; j += 128) sp[j] = pooled[(size_t)gi * (NGIN * U) + j];
    __syncthreads();
    float acc = bm1[c];
    for (int k = 0; k < NGIN * U; ++k) acc = fmaf(sp[k], Wm1[(size_t)k * 128 + c], acc);
    g[gi * 128 + c] = fmaxf(acc, 0.f);
}

__global__ __launch_bounds__(256) void mlp2_k(const float* __restrict__ g,
                                              const float* __restrict__ Wm2,
                                              const float* __restrict__ bm2,
                                              float* __restrict__ out) {
    int idx = blockIdx.x * 256 + threadIdx.x;
    int gi = idx >> 4, c = idx & 15;
    float acc = bm2[c];
    for (int k = 0; k < 128; ++k) acc = fmaf(g[gi * 128 + k], Wm2[k * 16 + c], acc);
    out[gi * 16 + c] = acc;
}

extern "C" void kernel_launch(void* const* d_in, const int* in_sizes, int n_in,
                              void* d_out, int out_size, void* d_ws, size_t ws_size,
                              hipStream_t stream) {
    const float* x   = (const float*)d_in[0];
    const int*   ei  = (const int*)d_in[1];
    const float* ew  = (const float*)d_in[2];
    const int*   gix = (const int*)d_in[3];
    const float* W1  = (const float*)d_in[4];
    const float* b1  = (const float*)d_in[5];
    const float* W2  = (const float*)d_in[6];
    const float* b2  = (const float*)d_in[7];
    const float* gam = (const float*)d_in[8];
    const float* bet = (const float*)d_in[9];
    const float* bmn = (const float*)d_in[10];
    const float* bvr = (const float*)d_in[11];
    const float* Wm1 = (const float*)d_in[12];
    const float* bm1 = (const float*)d_in[13];
    const float* Wm2 = (const float*)d_in[14];
    const float* bm2 = (const float*)d_in[15];
    float* out = (float*)d_out;

    // workspace layout (4B units unless noted):
    // hb bf16 [NN*U] | z bf16 [NN*U] | pooled f32 | g f32 | wfrag bf16 [6*16384] |
    // euv uint2 [NE] | rowptr [NN+1] | cursor [NN] | hist [NN] | bsum | boff
    unsigned short* hb = (unsigned short*)d_ws;
    unsigned short* z  = hb + (size_t)NN * U;
    float* pooled = (float*)(z + (size_t)NN * U);
    float* gbuf   = pooled + (size_t)NG * (NGIN * U);
    unsigned short* wfrag = (unsigned short*)(gbuf + (size_t)NG * 128);
    uint2* euv    = (uint2*)(wfrag + 6 * 16384);
    int*   rowptr = (int*)(euv + NE);
    int*   cursor = rowptr + (NN + 1);
    int*   hist   = cursor + NN;
    int*   bsum   = hist + NN;
    int*   boff   = bsum + NB;

    convert_k<<<(NN * U / 4 + 255) / 256, 256, 0, stream>>>(x, hb);
    hipMemsetAsync(hist, 0, NN * sizeof(int), stream);
    hist_k<<<(NE + 255) / 256, 256, 0, stream>>>(ei, hist);
    scan1_k<<<NB, 256, 0, stream>>>(hist, bsum);
    scan2_k<<<1, 64, 0, stream>>>(bsum, boff, rowptr);
    scan3_k<<<NB, 256, 0, stream>>>(hist, boff, rowptr, cursor);
    bin_k<<<(NE + 255) / 256, 256, 0, stream>>>(ei, ew, cursor, euv);
    wfrag_k<<<6, 256, 0, stream>>>(W1, W2, wfrag);
    hipMemsetAsync(pooled, 0, (size_t)NG * (NGIN * U) * sizeof(float), stream);

    const int dense_grid = (NN / 16 + 3) / 4;   // 4 waves x 16-row strips
    for (int i = 0; i < NGIN; ++i) {
        gather_k<<<NN / 4, 256, 0, stream>>>(hb, euv, rowptr, z);
        fused_dense_k<<<dense_grid, 256, 0, stream>>>(
            z, wfrag + (size_t)(2 * i) * 16384, wfrag + (size_t)(2 * i + 1) * 16384,
            b1 + i * U, b2 + i * U,
            gam + i * U, bet + i * U, bmn + i * U, bvr + i * U,
            gix, hb, pooled, i * U);
    }
    mlp1_k<<<NG, 128, 0, stream>>>(pooled, Wm1, bm1, gbuf);
    mlp2_k<<<(NG * 16) / 256, 256, 0, stream>>>(gbuf, Wm2, bm2, out);
}

// Round 7
// 378.838 us; speedup vs baseline: 12.4783x; 1.0121x over previous
//
#include <hip/hip_runtime.h>

#define NN 100000
#define NE 800000
#define NG 128
#define U  128
#define NGIN 3
#define SCAN_CHUNK 2048
#define NB ((NN + SCAN_CHUNK - 1) / SCAN_CHUNK)   // 49 blocks

typedef short bf16x8 __attribute__((ext_vector_type(8)));
typedef float f32x4 __attribute__((ext_vector_type(4)));

__device__ __forceinline__ unsigned short f2b(float f) {
    union { float f; unsigned u; } v; v.f = f;
    unsigned r = v.u + 0x7FFF + ((v.u >> 16) & 1);   // RNE
    return (unsigned short)(r >> 16);
}
__device__ __forceinline__ float blo(unsigned u) {
    union { unsigned u; float f; } v; v.u = u << 16; return v.f;
}
__device__ __forceinline__ float bhi(unsigned u) {
    union { unsigned u; float f; } v; v.u = u & 0xffff0000u; return v.f;
}

// ---------------------------------------------------------------------------
// x (fp32) -> hb (bf16)
// ---------------------------------------------------------------------------
__global__ __launch_bounds__(256) void convert_k(const float* __restrict__ x,
                                                 unsigned short* __restrict__ hb) {
    int i = blockIdx.x * 256 + threadIdx.x;
    if (i >= NN * U / 4) return;
    float4 v = reinterpret_cast<const float4*>(x)[i];
    uint2 o;
    o.x = (unsigned)f2b(v.x) | ((unsigned)f2b(v.y) << 16);
    o.y = (unsigned)f2b(v.z) | ((unsigned)f2b(v.w) << 16);
    reinterpret_cast<uint2*>(hb)[i] = o;
}

// ---------------------------------------------------------------------------
// pack W (fp32 [k][c]) into MFMA B-fragment order (bf16)
// frag[((ct*4+ks)*64+lane)*8+j] = W[ks*32+8*(lane>>4)+j][ct*16+(lane&15)]
// ---------------------------------------------------------------------------
__global__ __launch_bounds__(256) void wfrag_k(const float* __restrict__ W1,
                                               const float* __restrict__ W2,
                                               unsigned short* __restrict__ wfrag) {
    int b = blockIdx.x;
    const float* src = ((b & 1) ? W2 : W1) + (size_t)(b >> 1) * U * U;
    unsigned short* dst = wfrag + (size_t)b * 16384;
    for (int e = threadIdx.x; e < 16384; e += 256) {
        int j = e & 7, lane = (e >> 3) & 63, ks = (e >> 9) & 3, ct = e >> 11;
        int k = ks * 32 + ((lane >> 4) << 3) + j;
        int c = ct * 16 + (lane & 15);
        dst[e] = f2b(src[k * U + c]);
    }
}

// ---------------------------------------------------------------------------
// edge sort by dst: histogram -> 3-phase device scan -> bin
// ---------------------------------------------------------------------------
__global__ __launch_bounds__(256) void hist_k(const int* __restrict__ ei,
                                              int* __restrict__ hist) {
    int e = blockIdx.x * 256 + threadIdx.x;
    if (e < NE) atomicAdd(&hist[ei[e]], 1);
}

__global__ __launch_bounds__(256) void scan1_k(const int* __restrict__ hist,
                                               int* __restrict__ bsum) {
    int t = threadIdx.x;
    int base = blockIdx.x * SCAN_CHUNK + t * 8;
    int s = 0;
#pragma unroll
    for (int j = 0; j < 8; ++j) {
        int i = base + j;
        s += (i < NN) ? hist[i] : 0;
    }
#pragma unroll
    for (int off = 32; off > 0; off >>= 1) s += __shfl_down(s, off);
    __shared__ int ws[4];
    int lane = t & 63, wid = t >> 6;
    if (lane == 0) ws[wid] = s;
    __syncthreads();
    if (t == 0) bsum[blockIdx.x] = ws[0] + ws[1] + ws[2] + ws[3];
}

__global__ __launch_bounds__(64) void scan2_k(const int* __restrict__ bsum,
                                              int* __restrict__ boff,
                                              int* __restrict__ rowptr) {
    int lane = threadIdx.x;
    int v = (lane < NB) ? bsum[lane] : 0;
    int incl = v;
#pragma unroll
    for (int off = 1; off < 64; off <<= 1) {
        int n = __shfl_up(incl, off);
        if (lane >= off) incl += n;
    }
    if (lane < NB) boff[lane] = incl - v;
    if (lane == 0) rowptr[NN] = NE;
}

__global__ __launch_bounds__(256) void scan3_k(const int* __restrict__ hist,
                                               const int* __restrict__ boff,
                                               int* __restrict__ rowptr,
                                               int* __restrict__ cursor) {
    int t = threadIdx.x;
    int base = blockIdx.x * SCAN_CHUNK + t * 8;
    int v[8];
    int s = 0;
#pragma unroll
    for (int j = 0; j < 8; ++j) {
        int i = base + j;
        v[j] = (i < NN) ? hist[i] : 0;
        s += v[j];
    }
    int lane = t & 63, wid = t >> 6;
    int incl = s;
#pragma unroll
    for (int off = 1; off < 64; off <<= 1) {
        int n = __shfl_up(incl, off);
        if (lane >= off) incl += n;
    }
    __shared__ int ws[4];
    if (lane == 63) ws[wid] = incl;
    __syncthreads();
    if (t == 0) {
        int a = 0;
#pragma unroll
        for (int w = 0; w < 4; ++w) { int tmp = ws[w]; ws[w] = a; a += tmp; }
    }
    __syncthreads();
    int run = boff[blockIdx.x] + ws[wid] + (incl - s);
#pragma unroll
    for (int j = 0; j < 8; ++j) {
        int i = base + j;
        if (i < NN) { rowptr[i] = run; cursor[i] = run; }
        run += v[j];
    }
}

// packed 4B record per edge: (src << 15) | (bf16(w) & 0x7FFF)
// src < 2^17, w in [0,1) so bf16 sign bit is 0 -> lossless 15-bit encode of bf16(w)
__global__ __launch_bounds__(256) void bin_k(const int* __restrict__ ei,
                                             const float* __restrict__ ew,
                                             int* __restrict__ cursor,
                                             unsigned* __restrict__ esw) {
    int e = blockIdx.x * 256 + threadIdx.x;
    if (e >= NE) return;
    int d = ei[e];
    int pos = atomicAdd(&cursor[d], 1);
    unsigned short wb = f2b(ew[e]);           // sign bit 0 (w >= 0)
    esw[pos] = ((unsigned)ei[NE + e] << 15) | (unsigned)wb;
}

// ---------------------------------------------------------------------------
// gather: z[n] = 1.5*h[n] + sum h[src]*w
// wave per node; packed (src,w) pre-loaded vector-wide, shfl-broadcast;
// edges unrolled x4 with independent accumulators
// ---------------------------------------------------------------------------
__global__ __launch_bounds__(256) void gather_k(const unsigned short* __restrict__ h,
                                                const unsigned* __restrict__ esw,
                                                const int* __restrict__ rowptr,
                                                unsigned short* __restrict__ z) {
    int node = blockIdx.x * 4 + (threadIdx.x >> 6);
    if (node >= NN) return;
    int lane = threadIdx.x & 63;
    const unsigned* hp = reinterpret_cast<const unsigned*>(h);
    int beg = rowptr[node], end = rowptr[node + 1];

    float ax0 = 0.f, ay0 = 0.f, ax1 = 0.f, ay1 = 0.f;
    float ax2 = 0.f, ay2 = 0.f, ax3 = 0.f, ay3 = 0.f;

    for (int cb = beg; cb < end; cb += 64) {
        int n = min(end - cb, 64);
        unsigned rec = (lane < n) ? esw[cb + lane] : 0u;   // pad: src 0, w +0.0
        int sv = (int)(rec >> 15);
        float wv = __uint_as_float((rec & 0x7FFFu) << 16);
        for (int i = 0; i < n; i += 4) {
            int   s0 = __shfl(sv, i),     s1 = __shfl(sv, i + 1);
            int   s2 = __shfl(sv, i + 2), s3 = __shfl(sv, i + 3);
            float w0 = __shfl(wv, i),     w1 = __shfl(wv, i + 1);
            float w2 = __shfl(wv, i + 2), w3 = __shfl(wv, i + 3);
            unsigned h0 = hp[(size_t)s0 * 64 + lane];
            unsigned h1 = hp[(size_t)s1 * 64 + lane];
            unsigned h2 = hp[(size_t)s2 * 64 + lane];
            unsigned h3 = hp[(size_t)s3 * 64 + lane];
            ax0 = fmaf(blo(h0), w0, ax0); ay0 = fmaf(bhi(h0), w0, ay0);
            ax1 = fmaf(blo(h1), w1, ax1); ay1 = fmaf(bhi(h1), w1, ay1);
            ax2 = fmaf(blo(h2), w2, ax2); ay2 = fmaf(bhi(h2), w2, ay2);
            ax3 = fmaf(blo(h3), w3, ax3); ay3 = fmaf(bhi(h3), w3, ay3);
        }
    }
    float ax = (ax0 + ax1) + (ax2 + ax3);
    float ay = (ay0 + ay1) + (ay2 + ay3);
    unsigned hn = hp[(size_t)node * 64 + lane];
    ax = fmaf(1.5f, blo(hn), ax);
    ay = fmaf(1.5f, bhi(hn), ay);
    reinterpret_cast<unsigned*>(z)[(size_t)node * 64 + lane] =
        (unsigned)f2b(ax) | ((unsigned)f2b(ay) << 16);
}

// ---------------------------------------------------------------------------
// fused per-layer dense: h = relu(bn(relu(z@W1+b1)@W2+b2)) + pooled atomics
// wave owns TWO 16-row strips (32 rows): each B-frag load feeds 2 MFMAs
// z1 passes through wave-private LDS tiles, chunk-major layout
// ---------------------------------------------------------------------------
__global__ __launch_bounds__(256) void fused_dense_k(const unsigned short* __restrict__ A,
                                                     const unsigned short* __restrict__ wf1,
                                                     const unsigned short* __restrict__ wf2,
                                                     const float* __restrict__ bias1,
                                                     const float* __restrict__ bias2,
                                                     const float* __restrict__ gamma,
                                                     const float* __restrict__ beta,
                                                     const float* __restrict__ mean,
                                                     const float* __restrict__ var,
                                                     const int* __restrict__ gidx,
                                                     unsigned short* __restrict__ outp,
                                                     float* __restrict__ pooled,
                                                     int pool_off) {
    __shared__ unsigned short lds[4 * 2 * 2048];   // 4 waves x 2 strips x 4KB = 32KB
    const int lane = threadIdx.x & 63;
    const int wid = threadIdx.x >> 6;
    const int r0 = (blockIdx.x * 4 + wid) * 32;
    const int c = lane & 15;
    const int g = lane >> 4;

    bool valid[2];
    int rs[2];
#pragma unroll
    for (int s = 0; s < 2; ++s) {
        int r = r0 + s * 16;
        valid[s] = (r < NN);           // NN % 16 == 0: strips all-valid or all-invalid
        rs[s] = valid[s] ? r : 0;      // clamp for safe addressing
    }

    // ---- matmul 1: z1 = relu(A @ W1 + b1), both strips ----
    bf16x8 a[2][4];
#pragma unroll
    for (int s = 0; s < 2; ++s) {
        const size_t abase = (size_t)(rs[s] + c) * U + (g << 3);
#pragma unroll
        for (int ks = 0; ks < 4; ++ks)
            a[s][ks] = *reinterpret_cast<const bf16x8*>(A + abase + ks * 32);
    }

    f32x4 acc[2][8];
#pragma unroll
    for (int s = 0; s < 2; ++s)
#pragma unroll
        for (int ct = 0; ct < 8; ++ct) acc[s][ct] = (f32x4){0.f, 0.f, 0.f, 0.f};

#pragma unroll
    for (int ct = 0; ct < 8; ++ct)
#pragma unroll
        for (int ks = 0; ks < 4; ++ks) {
            bf16x8 b = *reinterpret_cast<const bf16x8*>(
                wf1 + (((ct * 4 + ks) * 64 + lane) << 3));
            acc[0][ct] = __builtin_amdgcn_mfma_f32_16x16x32_bf16(a[0][ks], b, acc[0][ct], 0, 0, 0);
            acc[1][ct] = __builtin_amdgcn_mfma_f32_16x16x32_bf16(a[1][ks], b, acc[1][ct], 0, 0, 0);
        }

    // epilogue 1 -> LDS (chunk-major): idx = chunk*128 + row*8 + (col&7)
#pragma unroll
    for (int s = 0; s < 2; ++s) {
        unsigned short* myl = lds + (wid * 2 + s) * 2048;
#pragma unroll
        for (int ct = 0; ct < 8; ++ct) {
            int col = ct * 16 + c;
            float bv = bias1[col];
            int chunk = col >> 3, within = col & 7;
#pragma unroll
            for (int j = 0; j < 4; ++j) {
                int row = (g << 2) + j;
                float v = fmaxf(acc[s][ct][j] + bv, 0.f);
                myl[chunk * 128 + row * 8 + within] = f2b(v);
            }
        }
    }
    __syncthreads();

    // ---- matmul 2: A2-frags from LDS ----
    bf16x8 a2[2][4];
#pragma unroll
    for (int s = 0; s < 2; ++s) {
        unsigned short* myl = lds + (wid * 2 + s) * 2048;
#pragma unroll
        for (int ks = 0; ks < 4; ++ks)
            a2[s][ks] = *reinterpret_cast<const bf16x8*>(myl + (ks * 4 + g) * 128 + c * 8);
    }

    f32x4 acc2[2][8];
#pragma unroll
    for (int s = 0; s < 2; ++s)
#pragma unroll
        for (int ct = 0; ct < 8; ++ct) acc2[s][ct] = (f32x4){0.f, 0.f, 0.f, 0.f};

#pragma unroll
    for (int ct = 0; ct < 8; ++ct)
#pragma unroll
        for (int ks = 0; ks < 4; ++ks) {
            bf16x8 b = *reinterpret_cast<const bf16x8*>(
                wf2 + (((ct * 4 + ks) * 64 + lane) << 3));
            acc2[0][ct] = __builtin_amdgcn_mfma_f32_16x16x32_bf16(a2[0][ks], b, acc2[0][ct], 0, 0, 0);
            acc2[1][ct] = __builtin_amdgcn_mfma_f32_16x16x32_bf16(a2[1][ks], b, acc2[1][ct], 0, 0, 0);
        }

    // ---- epilogue 2: bn + relu -> outp, pooled atomics ----
#pragma unroll
    for (int s = 0; s < 2; ++s) {
        const int rbase = rs[s] + (g << 2);
        int ga = gidx[rs[s]], gb = gidx[rs[s] + 15];
        bool uni = (ga == gb);
#pragma unroll
        for (int ct = 0; ct < 8; ++ct) {
            int col = ct * 16 + c;
            float bv = bias2[col];
            float scl = gamma[col] * rsqrtf(var[col] + 1e-3f);
            float mv = mean[col], bt = beta[col];
            float hv[4];
            float psum = 0.f;
#pragma unroll
            for (int j = 0; j < 4; ++j) {
                float v = fmaxf((acc2[s][ct][j] + bv - mv) * scl + bt, 0.f);
                hv[j] = v;
                psum += v;
                if (valid[s]) outp[(size_t)(rbase + j) * U + col] = f2b(v);
            }
            if (uni) {
                psum += __shfl_xor(psum, 16);
                psum += __shfl_xor(psum, 32);
                if (valid[s] && lane < 16)
                    unsafeAtomicAdd(&pooled[(size_t)ga * (NGIN * U) + pool_off + col], psum);
            } else if (valid[s]) {
#pragma unroll
                for (int j = 0; j < 4; ++j)
                    unsafeAtomicAdd(&pooled[(size_t)gidx[rbase + j] * (NGIN * U) + pool_off + col], hv[j]);
            }
        }
    }
}

// ---------------------------------------------------------------------------
// readout MLPs (fp32, tiny)
// ---------------------------------------------------------------------------
__global__ __launch_bounds__(128) void mlp1_k(const float* __restrict__ pooled,
                                              const float* __restrict__ Wm1,
                                              const float* __restrict__ bm1,
                                              float* __restrict__ g) {
    __shared__ float sp[NGIN * U];
    int gi = blockIdx.x, c = threadIdx.x;
    for (int j = c; j < NGIN * U; j += 128) sp[j] = pooled[(size_t)gi * (NGIN * U) + j];
    __syncthreads();
    float acc = bm1[c];
    for (int k = 0; k < NGIN * U; ++k) acc = fmaf(sp[k], Wm1[(size_t)k * 128 + c], acc);
    g[gi * 128 + c] = fmaxf(acc, 0.f);
}

__global__ __launch_bounds__(256) void mlp2_k(const float* __restrict__ g,
                                              const float* __restrict__ Wm2,
                                              const float* __restrict__ bm2,
                                              float* __restrict__ out) {
    int idx = blockIdx.x * 256 + threadIdx.x;
    int gi = idx >> 4, c = idx & 15;
    float acc = bm2[c];
    for (int k = 0; k < 128; ++k) acc = fmaf(g[gi * 128 + k], Wm2[k * 16 + c], acc);
    out[gi * 16 + c] = acc;
}

extern "C" void kernel_launch(void* const* d_in, const int* in_sizes, int n_in,
                              void* d_out, int out_size, void* d_ws, size_t ws_size,
                              hipStream_t stream) {
    const float* x   = (const float*)d_in[0];
    const int*   ei  = (const int*)d_in[1];
    const float* ew  = (const float*)d_in[2];
    const int*   gix = (const int*)d_in[3];
    const float* W1  = (const float*)d_in[4];
    const float* b1  = (const float*)d_in[5];
    const float* W2  = (const float*)d_in[6];
    const float* b2  = (const float*)d_in[7];
    const float* gam = (const float*)d_in[8];
    const float* bet = (const float*)d_in[9];
    const float* bmn = (const float*)d_in[10];
    const float* bvr = (const float*)d_in[11];
    const float* Wm1 = (const float*)d_in[12];
    const float* bm1 = (const float*)d_in[13];
    const float* Wm2 = (const float*)d_in[14];
    const float* bm2 = (const float*)d_in[15];
    float* out = (float*)d_out;

    // workspace layout:
    // hb bf16 [NN*U] | z bf16 [NN*U] | pooled f32 | g f32 | wfrag bf16 [6*16384] |
    // esw u32 [NE] | rowptr [NN+1] | cursor [NN] | hist [NN] | bsum | boff
    unsigned short* hb = (unsigned short*)d_ws;
    unsigned short* z  = hb + (size_t)NN * U;
    float* pooled = (float*)(z + (size_t)NN * U);
    float* gbuf   = pooled + (size_t)NG * (NGIN * U);
    unsigned short* wfrag = (unsigned short*)(gbuf + (size_t)NG * 128);
    unsigned* esw = (unsigned*)(wfrag + 6 * 16384);
    int*   rowptr = (int*)(esw + NE);
    int*   cursor = rowptr + (NN + 1);
    int*   hist   = cursor + NN;
    int*   bsum   = hist + NN;
    int*   boff   = bsum + NB;

    convert_k<<<(NN * U / 4 + 255) / 256, 256, 0, stream>>>(x, hb);
    hipMemsetAsync(hist, 0, NN * sizeof(int), stream);
    hist_k<<<(NE + 255) / 256, 256, 0, stream>>>(ei, hist);
    scan1_k<<<NB, 256, 0, stream>>>(hist, bsum);
    scan2_k<<<1, 64, 0, stream>>>(bsum, boff, rowptr);
    scan3_k<<<NB, 256, 0, stream>>>(hist, boff, rowptr, cursor);
    bin_k<<<(NE + 255) / 256, 256, 0, stream>>>(ei, ew, cursor, esw);
    wfrag_k<<<6, 256, 0, stream>>>(W1, W2, wfrag);
    hipMemsetAsync(pooled, 0, (size_t)NG * (NGIN * U) * sizeof(float), stream);

    const int dense_grid = (NN + 127) / 128;   // 4 waves x 2 strips x 16 rows
    for (int i = 0; i < NGIN; ++i) {
        gather_k<<<NN / 4, 256, 0, stream>>>(hb, esw, rowptr, z);
        fused_dense_k<<<dense_grid, 256, 0, stream>>>(
            z, wfrag + (size_t)(2 * i) * 16384, wfrag + (size_t)(2 * i + 1) * 16384,
            b1 + i * U, b2 + i * U,
            gam + i * U, bet + i * U, bmn + i * U, bvr + i * U,
            gix, hb, pooled, i * U);
    }
    mlp1_k<<<NG, 128, 0, stream>>>(pooled, Wm1, bm1, gbuf);
    mlp2_k<<<(NG * 16) / 256, 256, 0, stream>>>(gbuf, Wm2, bm2, out);
}

// Round 8
// 334.222 us; speedup vs baseline: 14.1440x; 1.1335x over previous
//
#include <hip/hip_runtime.h>

#define NN 100000
#define NE 800000
#define NG 128
#define U  128
#define NGIN 3
#define NBUCK 64
#define NPB 1563                 // ceil(NN / NBUCK); 64*1563 = 100032 >= NN
#define ACHUNK 4096
#define NAB ((NE + ACHUNK - 1) / ACHUNK)   // 196 phase-A blocks

typedef short bf16x8 __attribute__((ext_vector_type(8)));
typedef float f32x4 __attribute__((ext_vector_type(4)));

__device__ __forceinline__ unsigned short f2b(float f) {
    union { float f; unsigned u; } v; v.f = f;
    unsigned r = v.u + 0x7FFF + ((v.u >> 16) & 1);   // RNE
    return (unsigned short)(r >> 16);
}
__device__ __forceinline__ float blo(unsigned u) {
    union { unsigned u; float f; } v; v.u = u << 16; return v.f;
}
__device__ __forceinline__ float bhi(unsigned u) {
    union { unsigned u; float f; } v; v.u = u & 0xffff0000u; return v.f;
}

// ---------------------------------------------------------------------------
// x (fp32) -> hb (bf16)
// ---------------------------------------------------------------------------
__global__ __launch_bounds__(256) void convert_k(const float* __restrict__ x,
                                                 unsigned short* __restrict__ hb) {
    int i = blockIdx.x * 256 + threadIdx.x;
    if (i >= NN * U / 4) return;
    float4 v = reinterpret_cast<const float4*>(x)[i];
    uint2 o;
    o.x = (unsigned)f2b(v.x) | ((unsigned)f2b(v.y) << 16);
    o.y = (unsigned)f2b(v.z) | ((unsigned)f2b(v.w) << 16);
    reinterpret_cast<uint2*>(hb)[i] = o;
}

// ---------------------------------------------------------------------------
// pack W (fp32 [k][c]) into MFMA B-fragment order (bf16)
// ---------------------------------------------------------------------------
__global__ __launch_bounds__(256) void wfrag_k(const float* __restrict__ W1,
                                               const float* __restrict__ W2,
                                               unsigned short* __restrict__ wfrag) {
    int b = blockIdx.x;
    const float* src = ((b & 1) ? W2 : W1) + (size_t)(b >> 1) * U * U;
    unsigned short* dst = wfrag + (size_t)b * 16384;
    for (int e = threadIdx.x; e < 16384; e += 256) {
        int j = e & 7, lane = (e >> 3) & 63, ks = (e >> 9) & 3, ct = e >> 11;
        int k = ks * 32 + ((lane >> 4) << 3) + j;
        int c = ct * 16 + (lane & 15);
        dst[e] = f2b(src[k * U + c]);
    }
}

// ---------------------------------------------------------------------------
// CSR build, owner-computes:
//   bhist: 64-bucket histogram (LDS pre-aggregated)
//   bscan: 1-wave scan -> bucket offsets (bcur for phaseA, boff for phaseB)
//   phaseA: per-block segment reservation + dense 8B record writes
//   phaseB: per-bucket block: node hist + scan -> rowptr, local scatter of 4B recs
// ---------------------------------------------------------------------------
__global__ __launch_bounds__(256) void bhist_k(const int* __restrict__ ei,
                                               int* __restrict__ bcnt) {
    __shared__ int lh[NBUCK];
    int tid = threadIdx.x;
    if (tid < NBUCK) lh[tid] = 0;
    __syncthreads();
    int e0 = blockIdx.x * ACHUNK;
    int eend = min(e0 + ACHUNK, NE);
    for (int e = e0 + tid; e < eend; e += 256)
        atomicAdd(&lh[ei[e] / NPB], 1);
    __syncthreads();
    if (tid < NBUCK && lh[tid]) atomicAdd(&bcnt[tid], lh[tid]);
}

__global__ __launch_bounds__(64) void bscan_k(const int* __restrict__ bcnt,
                                              int* __restrict__ bcur,
                                              int* __restrict__ boff,
                                              int* __restrict__ rowptr) {
    int lane = threadIdx.x;
    int v = bcnt[lane];
    int incl = v;
#pragma unroll
    for (int off = 1; off < 64; off <<= 1) {
        int n = __shfl_up(incl, off);
        if (lane >= off) incl += n;
    }
    int excl = incl - v;
    bcur[lane] = excl;
    boff[lane] = excl;
    if (lane == 63) { boff[64] = incl; rowptr[NN] = NE; }
}

__global__ __launch_bounds__(256) void phaseA_k(const int* __restrict__ ei,
                                                const float* __restrict__ ew,
                                                int* __restrict__ bcur,
                                                uint2* __restrict__ tmp) {
    __shared__ int lh[NBUCK];
    int tid = threadIdx.x;
    if (tid < NBUCK) lh[tid] = 0;
    __syncthreads();
    int e0 = blockIdx.x * ACHUNK;
    int eend = min(e0 + ACHUNK, NE);
    // pass 1: chunk histogram
    for (int e = e0 + tid; e < eend; e += 256)
        atomicAdd(&lh[ei[e] / NPB], 1);
    __syncthreads();
    // reserve contiguous segments; lh becomes absolute cursor
    if (tid < NBUCK) {
        int c = lh[tid];
        lh[tid] = c ? atomicAdd(&bcur[tid], c) : 0;
    }
    __syncthreads();
    // pass 2: dense-ish writes into owned segments
    for (int e = e0 + tid; e < eend; e += 256) {
        int d = ei[e];
        int pos = atomicAdd(&lh[d / NPB], 1);
        uint2 r;
        r.x = ((unsigned)ei[NE + e] << 15) | (unsigned)f2b(ew[e]);
        r.y = (unsigned)d;
        tmp[pos] = r;
    }
}

__global__ __launch_bounds__(256) void phaseB_k(const uint2* __restrict__ tmp,
                                                const int* __restrict__ boff,
                                                int* __restrict__ rowptr,
                                                unsigned* __restrict__ esw) {
    __shared__ int cnt[1792];    // 256 threads x 7 slots (>= NPB), counts -> cursors
    __shared__ int ws[4];
    const int tid = threadIdx.x;
    const int b = blockIdx.x;
    const int n0 = b * NPB;
    const int npb = min(NPB, NN - n0);
    const int wbeg = boff[b], wend = boff[b + 1];

    for (int i = tid; i < 1792; i += 256) cnt[i] = 0;
    __syncthreads();
    // pass 1: per-node histogram of this bucket's edges
    for (int e = wbeg + tid; e < wend; e += 256)
        atomicAdd(&cnt[(int)tmp[e].y - n0], 1);
    __syncthreads();
    // exclusive scan over 1792 slots (7 contiguous per thread)
    int base = tid * 7;
    int v[7]; int s = 0;
#pragma unroll
    for (int k = 0; k < 7; ++k) { v[k] = cnt[base + k]; s += v[k]; }
    int lane = tid & 63, wid = tid >> 6;
    int incl = s;
#pragma unroll
    for (int off = 1; off < 64; off <<= 1) {
        int n = __shfl_up(incl, off);
        if (lane >= off) incl += n;
    }
    if (lane == 63) ws[wid] = incl;
    __syncthreads();
    if (tid == 0) {
        int a = 0;
#pragma unroll
        for (int w = 0; w < 4; ++w) { int t = ws[w]; ws[w] = a; a += t; }
    }
    __syncthreads();
    int run = wbeg + ws[wid] + (incl - s);   // absolute position
#pragma unroll
    for (int k = 0; k < 7; ++k) { cnt[base + k] = run; run += v[k]; }
    __syncthreads();
    // rowptr (coalesced)
    for (int i = tid; i < npb; i += 256) rowptr[n0 + i] = cnt[i];
    __syncthreads();
    // pass 2: scatter final 4B records inside owned window
    for (int e = wbeg + tid; e < wend; e += 256) {
        uint2 r = tmp[e];
        int pos = atomicAdd(&cnt[(int)r.y - n0], 1);
        esw[pos] = r.x;
    }
}

// ---------------------------------------------------------------------------
// gather: z[n] = 1.5*h[n] + sum h[src]*w
// wave per node; packed (src,w) pre-loaded vector-wide, shfl-broadcast;
// edges unrolled x4 with independent accumulators
// ---------------------------------------------------------------------------
__global__ __launch_bounds__(256) void gather_k(const unsigned short* __restrict__ h,
                                                const unsigned* __restrict__ esw,
                                                const int* __restrict__ rowptr,
                                                unsigned short* __restrict__ z) {
    int node = blockIdx.x * 4 + (threadIdx.x >> 6);
    if (node >= NN) return;
    int lane = threadIdx.x & 63;
    const unsigned* hp = reinterpret_cast<const unsigned*>(h);
    int beg = rowptr[node], end = rowptr[node + 1];

    float ax0 = 0.f, ay0 = 0.f, ax1 = 0.f, ay1 = 0.f;
    float ax2 = 0.f, ay2 = 0.f, ax3 = 0.f, ay3 = 0.f;

    for (int cb = beg; cb < end; cb += 64) {
        int n = min(end - cb, 64);
        unsigned rec = (lane < n) ? esw[cb + lane] : 0u;   // pad: src 0, w +0.0
        int sv = (int)(rec >> 15);
        float wv = __uint_as_float((rec & 0x7FFFu) << 16);
        for (int i = 0; i < n; i += 4) {
            int   s0 = __shfl(sv, i),     s1 = __shfl(sv, i + 1);
            int   s2 = __shfl(sv, i + 2), s3 = __shfl(sv, i + 3);
            float w0 = __shfl(wv, i),     w1 = __shfl(wv, i + 1);
            float w2 = __shfl(wv, i + 2), w3 = __shfl(wv, i + 3);
            unsigned h0 = hp[(size_t)s0 * 64 + lane];
            unsigned h1 = hp[(size_t)s1 * 64 + lane];
            unsigned h2 = hp[(size_t)s2 * 64 + lane];
            unsigned h3 = hp[(size_t)s3 * 64 + lane];
            ax0 = fmaf(blo(h0), w0, ax0); ay0 = fmaf(bhi(h0), w0, ay0);
            ax1 = fmaf(blo(h1), w1, ax1); ay1 = fmaf(bhi(h1), w1, ay1);
            ax2 = fmaf(blo(h2), w2, ax2); ay2 = fmaf(bhi(h2), w2, ay2);
            ax3 = fmaf(blo(h3), w3, ax3); ay3 = fmaf(bhi(h3), w3, ay3);
        }
    }
    float ax = (ax0 + ax1) + (ax2 + ax3);
    float ay = (ay0 + ay1) + (ay2 + ay3);
    unsigned hn = hp[(size_t)node * 64 + lane];
    ax = fmaf(1.5f, blo(hn), ax);
    ay = fmaf(1.5f, bhi(hn), ay);
    reinterpret_cast<unsigned*>(z)[(size_t)node * 64 + lane] =
        (unsigned)f2b(ax) | ((unsigned)f2b(ay) << 16);
}

// ---------------------------------------------------------------------------
// fused per-layer dense: h = relu(bn(relu(z@W1+b1)@W2+b2)) + pooled atomics
// wave owns TWO 16-row strips (32 rows); z1 via wave-private LDS, chunk-major
// ---------------------------------------------------------------------------
__global__ __launch_bounds__(256) void fused_dense_k(const unsigned short* __restrict__ A,
                                                     const unsigned short* __restrict__ wf1,
                                                     const unsigned short* __restrict__ wf2,
                                                     const float* __restrict__ bias1,
                                                     const float* __restrict__ bias2,
                                                     const float* __restrict__ gamma,
                                                     const float* __restrict__ beta,
                                                     const float* __restrict__ mean,
                                                     const float* __restrict__ var,
                                                     const int* __restrict__ gidx,
                                                     unsigned short* __restrict__ outp,
                                                     float* __restrict__ pooled,
                                                     int pool_off) {
    __shared__ unsigned short lds[4 * 2 * 2048];
    const int lane = threadIdx.x & 63;
    const int wid = threadIdx.x >> 6;
    const int r0 = (blockIdx.x * 4 + wid) * 32;
    const int c = lane & 15;
    const int g = lane >> 4;

    bool valid[2];
    int rs[2];
#pragma unroll
    for (int s = 0; s < 2; ++s) {
        int r = r0 + s * 16;
        valid[s] = (r < NN);
        rs[s] = valid[s] ? r : 0;
    }

    bf16x8 a[2][4];
#pragma unroll
    for (int s = 0; s < 2; ++s) {
        const size_t abase = (size_t)(rs[s] + c) * U + (g << 3);
#pragma unroll
        for (int ks = 0; ks < 4; ++ks)
            a[s][ks] = *reinterpret_cast<const bf16x8*>(A + abase + ks * 32);
    }

    f32x4 acc[2][8];
#pragma unroll
    for (int s = 0; s < 2; ++s)
#pragma unroll
        for (int ct = 0; ct < 8; ++ct) acc[s][ct] = (f32x4){0.f, 0.f, 0.f, 0.f};

#pragma unroll
    for (int ct = 0; ct < 8; ++ct)
#pragma unroll
        for (int ks = 0; ks < 4; ++ks) {
            bf16x8 b = *reinterpret_cast<const bf16x8*>(
                wf1 + (((ct * 4 + ks) * 64 + lane) << 3));
            acc[0][ct] = __builtin_amdgcn_mfma_f32_16x16x32_bf16(a[0][ks], b, acc[0][ct], 0, 0, 0);
            acc[1][ct] = __builtin_amdgcn_mfma_f32_16x16x32_bf16(a[1][ks], b, acc[1][ct], 0, 0, 0);
        }

#pragma unroll
    for (int s = 0; s < 2; ++s) {
        unsigned short* myl = lds + (wid * 2 + s) * 2048;
#pragma unroll
        for (int ct = 0; ct < 8; ++ct) {
            int col = ct * 16 + c;
            float bv = bias1[col];
            int chunk = col >> 3, within = col & 7;
#pragma unroll
            for (int j = 0; j < 4; ++j) {
                int row = (g << 2) + j;
                float v = fmaxf(acc[s][ct][j] + bv, 0.f);
                myl[chunk * 128 + row * 8 + within] = f2b(v);
            }
        }
    }
    __syncthreads();

    bf16x8 a2[2][4];
#pragma unroll
    for (int s = 0; s < 2; ++s) {
        unsigned short* myl = lds + (wid * 2 + s) * 2048;
#pragma unroll
        for (int ks = 0; ks < 4; ++ks)
            a2[s][ks] = *reinterpret_cast<const bf16x8*>(myl + (ks * 4 + g) * 128 + c * 8);
    }

    f32x4 acc2[2][8];
#pragma unroll
    for (int s = 0; s < 2; ++s)
#pragma unroll
        for (int ct = 0; ct < 8; ++ct) acc2[s][ct] = (f32x4){0.f, 0.f, 0.f, 0.f};

#pragma unroll
    for (int ct = 0; ct < 8; ++ct)
#pragma unroll
        for (int ks = 0; ks < 4; ++ks) {
            bf16x8 b = *reinterpret_cast<const bf16x8*>(
                wf2 + (((ct * 4 + ks) * 64 + lane) << 3));
            acc2[0][ct] = __builtin_amdgcn_mfma_f32_16x16x32_bf16(a2[0][ks], b, acc2[0][ct], 0, 0, 0);
            acc2[1][ct] = __builtin_amdgcn_mfma_f32_16x16x32_bf16(a2[1][ks], b, acc2[1][ct], 0, 0, 0);
        }

#pragma unroll
    for (int s = 0; s < 2; ++s) {
        const int rbase = rs[s] + (g << 2);
        int ga = gidx[rs[s]], gb = gidx[rs[s] + 15];
        bool uni = (ga == gb);
#pragma unroll
        for (int ct = 0; ct < 8; ++ct) {
            int col = ct * 16 + c;
            float bv = bias2[col];
            float scl = gamma[col] * rsqrtf(var[col] + 1e-3f);
            float mv = mean[col], bt = beta[col];
            float hv[4];
            float psum = 0.f;
#pragma unroll
            for (int j = 0; j < 4; ++j) {
                float v = fmaxf((acc2[s][ct][j] + bv - mv) * scl + bt, 0.f);
                hv[j] = v;
                psum += v;
                if (valid[s]) outp[(size_t)(rbase + j) * U + col] = f2b(v);
            }
            if (uni) {
                psum += __shfl_xor(psum, 16);
                psum += __shfl_xor(psum, 32);
                if (valid[s] && lane < 16)
                    unsafeAtomicAdd(&pooled[(size_t)ga * (NGIN * U) + pool_off + col], psum);
            } else if (valid[s]) {
#pragma unroll
                for (int j = 0; j < 4; ++j)
                    unsafeAtomicAdd(&pooled[(size_t)gidx[rbase + j] * (NGIN * U) + pool_off + col], hv[j]);
            }
        }
    }
}

// ---------------------------------------------------------------------------
// readout MLPs (fp32, tiny)
// ---------------------------------------------------------------------------
__global__ __launch_bounds__(128) void mlp1_k(const float* __restrict__ pooled,
                                              const float* __restrict__ Wm1,
                                              const float* __restrict__ bm1,
                                              float* __restrict__ g) {
    __shared__ float sp[NGIN * U];
    int gi = blockIdx.x, c = threadIdx.x;
    for (int j = c; j < NGIN * U; j += 128) sp[j] = pooled[(size_t)gi * (NGIN * U) + j];
    __syncthreads();
    float acc = bm1[c];
    for (int k = 0; k < NGIN * U; ++k) acc = fmaf(sp[k], Wm1[(size_t)k * 128 + c], acc);
    g[gi * 128 + c] = fmaxf(acc, 0.f);
}

__global__ __launch_bounds__(256) void mlp2_k(const float* __restrict__ g,
                                              const float* __restrict__ Wm2,
                                              const float* __restrict__ bm2,
                                              float* __restrict__ out) {
    int idx = blockIdx.x * 256 + threadIdx.x;
    int gi = idx >> 4, c = idx & 15;
    float acc = bm2[c];
    for (int k = 0; k < 128; ++k) acc = fmaf(g[gi * 128 + k], Wm2[k * 16 + c], acc);
    out[gi * 16 + c] = acc;
}

extern "C" void kernel_launch(void* const* d_in, const int* in_sizes, int n_in,
                              void* d_out, int out_size, void* d_ws, size_t ws_size,
                              hipStream_t stream) {
    const float* x   = (const float*)d_in[0];
    const int*   ei  = (const int*)d_in[1];
    const float* ew  = (const float*)d_in[2];
    const int*   gix = (const int*)d_in[3];
    const float* W1  = (const float*)d_in[4];
    const float* b1  = (const float*)d_in[5];
    const float* W2  = (const float*)d_in[6];
    const float* b2  = (const float*)d_in[7];
    const float* gam = (const float*)d_in[8];
    const float* bet = (const float*)d_in[9];
    const float* bmn = (const float*)d_in[10];
    const float* bvr = (const float*)d_in[11];
    const float* Wm1 = (const float*)d_in[12];
    const float* bm1 = (const float*)d_in[13];
    const float* Wm2 = (const float*)d_in[14];
    const float* bm2 = (const float*)d_in[15];
    float* out = (float*)d_out;

    // workspace layout:
    // hb bf16 [NN*U] | z bf16 [NN*U] | pooled f32 | g f32 | wfrag bf16 [6*16384] |
    // esw u32 [NE] | tmp uint2 [NE] | rowptr [NN+1] | bcnt[64] | bcur[64] | boff[65]
    unsigned short* hb = (unsigned short*)d_ws;
    unsigned short* z  = hb + (size_t)NN * U;
    float* pooled = (float*)(z + (size_t)NN * U);
    float* gbuf   = pooled + (size_t)NG * (NGIN * U);
    unsigned short* wfrag = (unsigned short*)(gbuf + (size_t)NG * 128);
    unsigned* esw = (unsigned*)(wfrag + 6 * 16384);
    uint2* tmp    = (uint2*)(esw + NE);
    int*   rowptr = (int*)(tmp + NE);
    int*   bcnt   = rowptr + (NN + 1);
    int*   bcur   = bcnt + NBUCK;
    int*   boff   = bcur + NBUCK;

    convert_k<<<(NN * U / 4 + 255) / 256, 256, 0, stream>>>(x, hb);
    hipMemsetAsync(bcnt, 0, NBUCK * sizeof(int), stream);
    bhist_k<<<NAB, 256, 0, stream>>>(ei, bcnt);
    bscan_k<<<1, 64, 0, stream>>>(bcnt, bcur, boff, rowptr);
    phaseA_k<<<NAB, 256, 0, stream>>>(ei, ew, bcur, tmp);
    phaseB_k<<<NBUCK, 256, 0, stream>>>(tmp, boff, rowptr, esw);
    wfrag_k<<<6, 256, 0, stream>>>(W1, W2, wfrag);
    hipMemsetAsync(pooled, 0, (size_t)NG * (NGIN * U) * sizeof(float), stream);

    const int dense_grid = (NN + 127) / 128;
    for (int i = 0; i < NGIN; ++i) {
        gather_k<<<NN / 4, 256, 0, stream>>>(hb, esw, rowptr, z);
        fused_dense_k<<<dense_grid, 256, 0, stream>>>(
            z, wfrag + (size_t)(2 * i) * 16384, wfrag + (size_t)(2 * i + 1) * 16384,
            b1 + i * U, b2 + i * U,
            gam + i * U, bet + i * U, bmn + i * U, bvr + i * U,
            gix, hb, pooled, i * U);
    }
    mlp1_k<<<NG, 128, 0, stream>>>(pooled, Wm1, bm1, gbuf);
    mlp2_k<<<(NG * 16) / 256, 256, 0, stream>>>(gbuf, Wm2, bm2, out);
}